// Round 2
// baseline (520.439 us; speedup 1.0000x reference)
//
#include <hip/hip_runtime.h>

#define BR 64
#define EC 131072
#define BINS 4096
#define CAP 4096
#define CHUNKS 16
#define CHUNK_V (EC / CHUNKS / 4)   // float4 per chunk = 2048

// ws word-offset layout
#define WS_GMAX 0
#define WS_ACTIVE 1
#define WS_TOACT 2
#define WS_B1 8        // +row
#define WS_KREM 72     // +row
#define WS_UT 136      // +row
#define WS_CUT 200     // +row
#define WS_CCNT 264    // +row
#define WS_UT2 512     // +row (correction branch)
#define WS_CUT2 576    // +row
#define HIST_OFF 1024
#define CAND_U_OFF (HIST_OFF + BR * BINS)
#define CAND_I_OFF (CAND_U_OFF + BR * CAP)
#define ZERO_BYTES ((size_t)CAND_U_OFF * 4)   // scalars + per-row slots + histograms

// Monotonic float->uint mapping (order-preserving, bijective)
__device__ __forceinline__ unsigned map_f(float f) {
    unsigned b = __float_as_uint(f);
    return (b & 0x80000000u) ? ~b : (b | 0x80000000u);
}
__device__ __forceinline__ float unmap_f(unsigned u) {
    unsigned b = (u & 0x80000000u) ? (u & 0x7FFFFFFFu) : ~u;
    return __uint_as_float(b);
}

// EXACT numpy-op-sequence value computation; contract(off) so every kernel
// computes bit-identical values.
__device__ __forceinline__ void compute_vals(float x, float bt, float gmax, float bp,
                                             float* nb, float* bo) {
#pragma clang fp contract(off)
    float q = x / gmax;
    float t = 1.0f - q;
    float p = t * bp;
    float nbv = bt + p;
    *nb = nbv;
    *bo = fmaxf(x, 0.0f) + nbv;
}

__device__ __forceinline__ unsigned umax_(unsigned a, unsigned b) { return a > b ? a : b; }

// ---------------- Kernel: global max of x ----------------
__global__ void kmax(const float4* __restrict__ x4, unsigned* ws, int nvec) {
    unsigned m = 0;
    int stride = gridDim.x * blockDim.x;
    for (int v = blockIdx.x * blockDim.x + threadIdx.x; v < nvec; v += stride) {
        float4 xv = x4[v];
        m = umax_(m, map_f(xv.x)); m = umax_(m, map_f(xv.y));
        m = umax_(m, map_f(xv.z)); m = umax_(m, map_f(xv.w));
    }
    for (int off = 32; off; off >>= 1) m = umax_(m, __shfl_down(m, off, 64));
    __shared__ unsigned sm[16];
    int wid = threadIdx.x >> 6, lane = threadIdx.x & 63;
    if (lane == 0) sm[wid] = m;
    __syncthreads();
    if (threadIdx.x == 0) {
        unsigned mm = sm[0];
        int nw = blockDim.x >> 6;
        for (int w = 1; w < nw; ++w) mm = umax_(mm, sm[w]);
        atomicMax(ws, mm);
    }
}

// ---------------- Kernel: per-row 4096-bin histogram of top-12 bits ----------------
__global__ __launch_bounds__(256) void khist(const float4* __restrict__ x4,
                                             const float4* __restrict__ bt4,
                                             const float* __restrict__ bp_p,
                                             unsigned* __restrict__ ws) {
    __shared__ unsigned h[BINS];
    for (int i = threadIdx.x; i < BINS; i += 256) h[i] = 0;
    int row = blockIdx.x >> 4;
    int chunk = blockIdx.x & (CHUNKS - 1);
    float gmax = unmap_f(ws[WS_GMAX]);
    float bp = *bp_p;
    size_t base = (size_t)row * (EC / 4) + (size_t)chunk * CHUNK_V;
    __syncthreads();
    for (int v = threadIdx.x; v < CHUNK_V; v += 256) {
        float4 xv = x4[base + v];
        float4 bv = bt4[base + v];
        float xs[4] = {xv.x, xv.y, xv.z, xv.w};
        float bs[4] = {bv.x, bv.y, bv.z, bv.w};
        #pragma unroll
        for (int j = 0; j < 4; ++j) {
            float nb, bo;
            compute_vals(xs[j], bs[j], gmax, bp, &nb, &bo);
            atomicAdd(&h[map_f(bo) >> 20], 1u);
        }
    }
    __syncthreads();
    unsigned* gh = ws + HIST_OFF + (size_t)row * BINS;
    for (int i = threadIdx.x; i < BINS; i += 256)
        if (h[i]) atomicAdd(&gh[i], h[i]);
}

// ---------------- Kernel: find bin containing K-th largest, per row ----------------
__global__ __launch_bounds__(256) void kfind(const float* __restrict__ sp,
                                             unsigned* __restrict__ ws) {
    int row = blockIdx.x;
    unsigned K = (unsigned)ceilf(sp[1] * (float)EC);
    if (K > EC) K = EC;
    if (K == 0) K = 1;
    const unsigned* gh = ws + HIST_OFF + (size_t)row * BINS;
    __shared__ unsigned ssum[256];
    __shared__ unsigned sabove[256];
    int t = threadIdx.x;
    unsigned hv[16];
    unsigned s = 0;
    #pragma unroll
    for (int j = 0; j < 16; ++j) { hv[j] = gh[t * 16 + j]; s += hv[j]; }
    ssum[t] = s;
    __syncthreads();
    if (t == 0) {
        unsigned acc = 0;
        for (int q = 255; q >= 0; --q) { sabove[q] = acc; acc += ssum[q]; }
    }
    __syncthreads();
    unsigned cum = sabove[t];  // count in bins strictly above this thread's segment
    for (int j = 15; j >= 0; --j) {
        unsigned h = hv[j];
        if (cum < K && cum + h >= K) {
            ws[WS_B1 + row] = (unsigned)(t * 16 + j);
            ws[WS_KREM + row] = K - cum;
        }
        cum += h;
    }
}

// ---------------- Kernel: collect candidates in the selected bin ----------------
__global__ __launch_bounds__(256) void kcollect(const float4* __restrict__ x4,
                                                const float4* __restrict__ bt4,
                                                const float* __restrict__ bp_p,
                                                unsigned* __restrict__ ws) {
    int row = blockIdx.x >> 4;
    int chunk = blockIdx.x & (CHUNKS - 1);
    unsigned b1 = ws[WS_B1 + row];
    float gmax = unmap_f(ws[WS_GMAX]);
    float bp = *bp_p;
    unsigned* cu = ws + CAND_U_OFF + (size_t)row * CAP;
    unsigned* ci = ws + CAND_I_OFF + (size_t)row * CAP;
    size_t base = (size_t)row * (EC / 4) + (size_t)chunk * CHUNK_V;
    int ebase = chunk * (EC / CHUNKS);
    for (int v = threadIdx.x; v < CHUNK_V; v += 256) {
        float4 xv = x4[base + v];
        float4 bv = bt4[base + v];
        float xs[4] = {xv.x, xv.y, xv.z, xv.w};
        float bs[4] = {bv.x, bv.y, bv.z, bv.w};
        #pragma unroll
        for (int j = 0; j < 4; ++j) {
            float nb, bo;
            compute_vals(xs[j], bs[j], gmax, bp, &nb, &bo);
            unsigned u = map_f(bo);
            if ((u >> 20) == b1) {
                unsigned pos = atomicAdd(&ws[WS_CCNT + row], 1u);
                if (pos < CAP) { cu[pos] = u; ci[pos] = (unsigned)(ebase + v * 4 + j); }
            }
        }
    }
}

// ---------------- Kernel: exact select + stable tie-cut among candidates ----------------
__global__ __launch_bounds__(256) void kfinal(unsigned* __restrict__ ws) {
    int row = blockIdx.x;
    unsigned n = ws[WS_CCNT + row];
    if (n > CAP) n = CAP;
    unsigned K = ws[WS_KREM + row];
    const unsigned* cu = ws + CAND_U_OFF + (size_t)row * CAP;
    const unsigned* ci = ws + CAND_I_OFF + (size_t)row * CAP;
    __shared__ unsigned su[CAP];
    __shared__ unsigned hist[256];
    __shared__ unsigned sb[2];
    for (unsigned i = threadIdx.x; i < n; i += 256) su[i] = cu[i];
    __syncthreads();
    unsigned prefix = 0, Kp = K;
    for (int pass = 0; pass < 4; ++pass) {
        int shift = 24 - 8 * pass;
        hist[threadIdx.x] = 0;
        __syncthreads();
        for (unsigned i = threadIdx.x; i < n; i += 256) {
            unsigned u = su[i];
            bool match = (pass == 0) || ((u >> (32 - 8 * pass)) == prefix);
            if (match) atomicAdd(&hist[(u >> shift) & 0xFFu], 1u);
        }
        __syncthreads();
        if (threadIdx.x == 0) {
            unsigned cum = 0, bsel = 0, krem = Kp;
            for (int b = 255; b >= 0; --b) {
                unsigned h = hist[b];
                if (cum + h >= Kp) { bsel = (unsigned)b; krem = Kp - cum; break; }
                cum += h;
            }
            sb[0] = (prefix << 8) | bsel;
            sb[1] = krem;
        }
        __syncthreads();
        prefix = sb[0];
        Kp = sb[1];
        __syncthreads();
    }
    unsigned u_t = prefix, krem2 = Kp;
    // cut = krem2-th smallest original index among candidates equal to u_t
    for (unsigned i = threadIdx.x; i < n; i += 256) {
        if (su[i] == u_t) {
            unsigned myidx = ci[i];
            unsigned r = 0;
            for (unsigned j = 0; j < n; ++j)
                if (su[j] == u_t && ci[j] < myidx) ++r;
            if (r == krem2 - 1) {
                ws[WS_UT + row] = u_t;
                ws[WS_CUT + row] = myidx;
            }
        }
    }
}

// ---------------- Kernel: mark + write both outputs + count active ----------------
__global__ void kmark(const float4* __restrict__ x4, const float4* __restrict__ bt4,
                      const float* __restrict__ bp_p, unsigned* ws,
                      float4* __restrict__ out4, float4* __restrict__ fb4) {
    float gmax = unmap_f(ws[WS_GMAX]);
    float bp = *bp_p;
    unsigned cnt = 0;
    const size_t nvec = (size_t)BR * EC / 4;
    size_t stride = (size_t)gridDim.x * blockDim.x;
    for (size_t v = (size_t)blockIdx.x * blockDim.x + threadIdx.x; v < nvec; v += stride) {
        size_t e0 = v << 2;
        int row = (int)(e0 >> 17);
        int col = (int)(e0 & (size_t)(EC - 1));
        unsigned u_t = ws[WS_UT + row];
        int cut = (int)ws[WS_CUT + row];
        float4 xv = x4[v], bv = bt4[v];
        float xarr[4] = {xv.x, xv.y, xv.z, xv.w};
        float barr[4] = {bv.x, bv.y, bv.z, bv.w};
        float o[4], f[4];
        #pragma unroll
        for (int j = 0; j < 4; ++j) {
            float nb, bo;
            compute_vals(xarr[j], barr[j], gmax, bp, &nb, &bo);
            unsigned u = map_f(bo);
            bool sel = (u > u_t) || ((u == u_t) && ((col + j) <= cut));
            bool saved = sel && (u > 0x80000000u);  // boosted > 0
            o[j] = saved ? 1.0f : 0.0f;
            f[j] = saved ? 0.0f : nb;
            cnt += saved ? 1u : 0u;
        }
        out4[v] = make_float4(o[0], o[1], o[2], o[3]);
        fb4[v] = make_float4(f[0], f[1], f[2], f[3]);
    }
    for (int off = 32; off; off >>= 1) cnt += __shfl_down(cnt, off, 64);
    __shared__ unsigned sc;
    if (threadIdx.x == 0) sc = 0;
    __syncthreads();
    if ((threadIdx.x & 63) == 0) atomicAdd(&sc, cnt);
    __syncthreads();
    if (threadIdx.x == 0) atomicAdd(&ws[WS_ACTIVE], sc);
}

// ---------------- Kernel: compute to_activate ----------------
__global__ void kneed(const float* __restrict__ sp, unsigned* ws) {
    if (threadIdx.x == 0 && blockIdx.x == 0) {
        float min_active = floorf(sp[0] * (float)EC);
        float active = (float)ws[WS_ACTIVE];
        ws[WS_TOACT] = (active < min_active) ? (unsigned)ceilf(min_active - active) : 0u;
    }
}

// ---------------- Correction branch: per-row select on new_boost (gated, dead here) ----
__global__ __launch_bounds__(1024) void kselect_nb(
        const float* __restrict__ x, const float* __restrict__ bt,
        const float* __restrict__ bp_p, unsigned* ws) {
    unsigned K = ws[WS_TOACT];
    if (K == 0) return;
    if (K > EC) K = EC;
    int row = blockIdx.x;
    float gmax = unmap_f(ws[WS_GMAX]);
    float bp = *bp_p;
    const float4* xr4 = (const float4*)(x + (size_t)row * EC);
    const float4* br4 = (const float4*)(bt + (size_t)row * EC);

    __shared__ unsigned hist[256];
    __shared__ unsigned sb[2];

    unsigned prefix = 0;
    unsigned Kp = K;
    for (int pass = 0; pass < 4; ++pass) {
        const int shift = 24 - 8 * pass;
        for (int i = threadIdx.x; i < 256; i += blockDim.x) hist[i] = 0;
        __syncthreads();
        for (int v = threadIdx.x; v < EC / 4; v += blockDim.x) {
            float4 xv = xr4[v];
            float4 bv = br4[v];
            float xs[4] = {xv.x, xv.y, xv.z, xv.w};
            float bs[4] = {bv.x, bv.y, bv.z, bv.w};
            #pragma unroll
            for (int j = 0; j < 4; ++j) {
                float nb, bo;
                compute_vals(xs[j], bs[j], gmax, bp, &nb, &bo);
                unsigned u = map_f(nb);
                bool match = (pass == 0) || ((u >> (32 - 8 * pass)) == prefix);
                if (match) atomicAdd(&hist[(u >> shift) & 0xFFu], 1u);
            }
        }
        __syncthreads();
        if (threadIdx.x == 0) {
            unsigned cum = 0, bsel = 0, krem = Kp;
            for (int b = 255; b >= 0; --b) {
                unsigned h = hist[b];
                if (cum + h >= Kp) { bsel = (unsigned)b; krem = Kp - cum; break; }
                cum += h;
            }
            sb[0] = (prefix << 8) | bsel;
            sb[1] = krem;
        }
        __syncthreads();
        prefix = sb[0];
        Kp = sb[1];
        __syncthreads();
    }
    unsigned u_t = prefix;
    unsigned ties = Kp;

    __shared__ unsigned s_wcnt[16];
    __shared__ unsigned s_run;
    __shared__ int s_cut;
    if (threadIdx.x == 0) { s_run = 0; s_cut = -1; }
    __syncthreads();
    int nw = (int)blockDim.x >> 6;
    int wid = threadIdx.x >> 6, lane = threadIdx.x & 63;
    const float* xs = x + (size_t)row * EC;
    const float* bs = bt + (size_t)row * EC;
    for (int base0 = 0; base0 < EC; base0 += blockDim.x) {
        int i = base0 + threadIdx.x;
        bool eq = false;
        if (i < EC) {
            float nb, bo;
            compute_vals(xs[i], bs[i], gmax, bp, &nb, &bo);
            eq = (map_f(nb) == u_t);
        }
        unsigned long long bal = __ballot(eq);
        if (lane == 0) s_wcnt[wid] = (unsigned)__popcll(bal);
        __syncthreads();
        unsigned run = s_run;
        unsigned wpre = 0;
        for (int w = 0; w < wid; ++w) wpre += s_wcnt[w];
        if (eq) {
            unsigned r = run + wpre + (unsigned)__popcll(bal & ((1ull << lane) - 1ull));
            if (r == ties - 1) s_cut = i;
        }
        __syncthreads();
        if (threadIdx.x == 0) {
            unsigned tot = 0;
            for (int w = 0; w < nw; ++w) tot += s_wcnt[w];
            s_run = run + tot;
        }
        __syncthreads();
        if (s_run >= ties) break;
    }
    if (threadIdx.x == 0) {
        ws[WS_UT2 + row] = u_t;
        ws[WS_CUT2 + row] = (unsigned)s_cut;
    }
}

// ---------------- Correction apply (gated, dead here) ----------------
__global__ void kfix(const float4* __restrict__ x4, const float4* __restrict__ bt4,
                     const float* __restrict__ bp_p, const unsigned* __restrict__ ws,
                     float* __restrict__ out, float* __restrict__ fb) {
    if (ws[WS_TOACT] == 0) return;
    float gmax = unmap_f(ws[WS_GMAX]);
    float bp = *bp_p;
    const size_t nvec = (size_t)BR * EC / 4;
    size_t stride = (size_t)gridDim.x * blockDim.x;
    for (size_t v = (size_t)blockIdx.x * blockDim.x + threadIdx.x; v < nvec; v += stride) {
        size_t e0 = v << 2;
        int row = (int)(e0 >> 17);
        int col = (int)(e0 & (size_t)(EC - 1));
        unsigned u_t = ws[WS_UT2 + row];
        int cut = (int)ws[WS_CUT2 + row];
        float4 xv = x4[v], bv = bt4[v];
        float xarr[4] = {xv.x, xv.y, xv.z, xv.w};
        float barr[4] = {bv.x, bv.y, bv.z, bv.w};
        #pragma unroll
        for (int j = 0; j < 4; ++j) {
            float nb, bo;
            compute_vals(xarr[j], barr[j], gmax, bp, &nb, &bo);
            unsigned u = map_f(nb);
            if (u > u_t || (u == u_t && (col + j) <= cut)) {
                out[e0 + j] = 1.0f;
                fb[e0 + j] = 0.0f;
            }
        }
    }
}

extern "C" void kernel_launch(void* const* d_in, const int* in_sizes, int n_in,
                              void* d_out, int out_size, void* d_ws, size_t ws_size,
                              hipStream_t stream) {
    const float* x  = (const float*)d_in[0];
    const float* bt = (const float*)d_in[1];
    const float* sp = (const float*)d_in[2];
    const float* bp = (const float*)d_in[3];
    float* out = (float*)d_out;
    float* fb  = out + (size_t)BR * EC;
    unsigned* ws = (unsigned*)d_ws;

    hipMemsetAsync(d_ws, 0, ZERO_BYTES, stream);

    kmax<<<2048, 256, 0, stream>>>((const float4*)x, ws, BR * EC / 4);
    khist<<<BR * CHUNKS, 256, 0, stream>>>((const float4*)x, (const float4*)bt, bp, ws);
    kfind<<<BR, 256, 0, stream>>>(sp, ws);
    kcollect<<<BR * CHUNKS, 256, 0, stream>>>((const float4*)x, (const float4*)bt, bp, ws);
    kfinal<<<BR, 256, 0, stream>>>(ws);
    kmark<<<2048, 256, 0, stream>>>((const float4*)x, (const float4*)bt, bp, ws,
                                    (float4*)out, (float4*)fb);
    kneed<<<1, 64, 0, stream>>>(sp, ws);
    kselect_nb<<<BR, 1024, 0, stream>>>(x, bt, bp, ws);
    kfix<<<2048, 256, 0, stream>>>((const float4*)x, (const float4*)bt, bp, ws, out, fb);
}

// Round 3
// 216.893 us; speedup vs baseline: 2.3995x; 2.3995x over previous
//
#include <hip/hip_runtime.h>

#define BR 64
#define EC 131072
#define BINS 4096
#define CAP 4096
#define LCAP 1024
#define CHUNKS 16
#define CHUNK_V (EC / CHUNKS / 4)   // float4 per chunk = 2048

// ws word-offset layout
#define WS_GMAX 0
#define WS_ACTIVE 1
#define WS_TOACT 2
#define WS_B1 8        // +row
#define WS_KREM 72     // +row
#define WS_UT 136      // +row
#define WS_CUT 200     // +row
#define WS_CCNT 264    // +row
#define WS_UT2 512     // +row (correction branch)
#define WS_CUT2 576    // +row
#define HIST_OFF 1024
#define CAND_U_OFF (HIST_OFF + BR * BINS)
#define CAND_I_OFF (CAND_U_OFF + BR * CAP)
#define ZERO_BYTES ((size_t)CAND_U_OFF * 4)   // scalars + per-row slots + histograms

// Monotonic float->uint mapping (order-preserving, bijective)
__device__ __forceinline__ unsigned map_f(float f) {
    unsigned b = __float_as_uint(f);
    return (b & 0x80000000u) ? ~b : (b | 0x80000000u);
}
__device__ __forceinline__ float unmap_f(unsigned u) {
    unsigned b = (u & 0x80000000u) ? (u & 0x7FFFFFFFu) : ~u;
    return __uint_as_float(b);
}

// EXACT numpy-op-sequence value computation; contract(off) so every kernel
// computes bit-identical values.
__device__ __forceinline__ void compute_vals(float x, float bt, float gmax, float bp,
                                             float* nb, float* bo) {
#pragma clang fp contract(off)
    float q = x / gmax;
    float t = 1.0f - q;
    float p = t * bp;
    float nbv = bt + p;
    *nb = nbv;
    *bo = fmaxf(x, 0.0f) + nbv;
}

__device__ __forceinline__ unsigned umax_(unsigned a, unsigned b) { return a > b ? a : b; }

// ---------------- Kernel: global max of x ----------------
__global__ void kmax(const float4* __restrict__ x4, unsigned* ws, int nvec) {
    unsigned m = 0;
    int stride = gridDim.x * blockDim.x;
    for (int v = blockIdx.x * blockDim.x + threadIdx.x; v < nvec; v += stride) {
        float4 xv = x4[v];
        m = umax_(m, map_f(xv.x)); m = umax_(m, map_f(xv.y));
        m = umax_(m, map_f(xv.z)); m = umax_(m, map_f(xv.w));
    }
    for (int off = 32; off; off >>= 1) m = umax_(m, __shfl_down(m, off, 64));
    __shared__ unsigned sm[16];
    int wid = threadIdx.x >> 6, lane = threadIdx.x & 63;
    if (lane == 0) sm[wid] = m;
    __syncthreads();
    if (threadIdx.x == 0) {
        unsigned mm = sm[0];
        int nw = blockDim.x >> 6;
        for (int w = 1; w < nw; ++w) mm = umax_(mm, sm[w]);
        atomicMax(ws, mm);
    }
}

// ---------------- Kernel: per-row 4096-bin histogram of top-12 bits ----------------
// LDS privatized per wave-pair (2 copies) to cut same-address LDS atomic
// serialization; global merge rotated per chunk to decorrelate hot addresses.
__global__ __launch_bounds__(256) void khist(const float4* __restrict__ x4,
                                             const float4* __restrict__ bt4,
                                             const float* __restrict__ bp_p,
                                             unsigned* __restrict__ ws) {
    __shared__ unsigned h[2][BINS];
    for (int i = threadIdx.x; i < 2 * BINS; i += 256) h[0][i] = 0;
    int row = blockIdx.x >> 4;
    int chunk = blockIdx.x & (CHUNKS - 1);
    int cpy = threadIdx.x >> 7;   // wave-pair id
    float gmax = unmap_f(ws[WS_GMAX]);
    float bp = *bp_p;
    size_t base = (size_t)row * (EC / 4) + (size_t)chunk * CHUNK_V;
    __syncthreads();
    for (int v = threadIdx.x; v < CHUNK_V; v += 256) {
        float4 xv = x4[base + v];
        float4 bv = bt4[base + v];
        float xs[4] = {xv.x, xv.y, xv.z, xv.w};
        float bs[4] = {bv.x, bv.y, bv.z, bv.w};
        #pragma unroll
        for (int j = 0; j < 4; ++j) {
            float nb, bo;
            compute_vals(xs[j], bs[j], gmax, bp, &nb, &bo);
            atomicAdd(&h[cpy][map_f(bo) >> 20], 1u);
        }
    }
    __syncthreads();
    unsigned* gh = ws + HIST_OFF + (size_t)row * BINS;
    int rot = chunk * 256;
    for (int i0 = threadIdx.x; i0 < BINS; i0 += 256) {
        int i = (i0 + rot) & (BINS - 1);
        unsigned v = h[0][i] + h[1][i];
        if (v) atomicAdd(&gh[i], v);   // no return value -> fire-and-forget
    }
}

// ---------------- Kernel: find bin containing K-th largest, per row ----------------
__global__ __launch_bounds__(256) void kfind(const float* __restrict__ sp,
                                             unsigned* __restrict__ ws) {
    int row = blockIdx.x;
    unsigned K = (unsigned)ceilf(sp[1] * (float)EC);
    if (K > EC) K = EC;
    if (K == 0) K = 1;
    const unsigned* gh = ws + HIST_OFF + (size_t)row * BINS;
    __shared__ unsigned ssum[256];
    __shared__ unsigned sabove[256];
    int t = threadIdx.x;
    unsigned hv[16];
    unsigned s = 0;
    #pragma unroll
    for (int j = 0; j < 16; ++j) { hv[j] = gh[t * 16 + j]; s += hv[j]; }
    ssum[t] = s;
    __syncthreads();
    if (t == 0) {
        unsigned acc = 0;
        for (int q = 255; q >= 0; --q) { sabove[q] = acc; acc += ssum[q]; }
    }
    __syncthreads();
    unsigned cum = sabove[t];  // count in bins strictly above this thread's segment
    for (int j = 15; j >= 0; --j) {
        unsigned h = hv[j];
        if (cum < K && cum + h >= K) {
            ws[WS_B1 + row] = (unsigned)(t * 16 + j);
            ws[WS_KREM + row] = K - cum;
        }
        cum += h;
    }
}

// ---------------- Kernel: collect candidates (block-aggregated reservation) -------
__global__ __launch_bounds__(256) void kcollect(const float4* __restrict__ x4,
                                                const float4* __restrict__ bt4,
                                                const float* __restrict__ bp_p,
                                                unsigned* __restrict__ ws) {
    __shared__ unsigned lu[LCAP], li[LCAP];
    __shared__ unsigned lcnt, gbase;
    if (threadIdx.x == 0) lcnt = 0;
    int row = blockIdx.x >> 4;
    int chunk = blockIdx.x & (CHUNKS - 1);
    unsigned b1 = ws[WS_B1 + row];
    float gmax = unmap_f(ws[WS_GMAX]);
    float bp = *bp_p;
    unsigned* cu = ws + CAND_U_OFF + (size_t)row * CAP;
    unsigned* ci = ws + CAND_I_OFF + (size_t)row * CAP;
    size_t base = (size_t)row * (EC / 4) + (size_t)chunk * CHUNK_V;
    int ebase = chunk * (EC / CHUNKS);
    __syncthreads();
    for (int v = threadIdx.x; v < CHUNK_V; v += 256) {
        float4 xv = x4[base + v];
        float4 bv = bt4[base + v];
        float xs[4] = {xv.x, xv.y, xv.z, xv.w};
        float bs[4] = {bv.x, bv.y, bv.z, bv.w};
        #pragma unroll
        for (int j = 0; j < 4; ++j) {
            float nb, bo;
            compute_vals(xs[j], bs[j], gmax, bp, &nb, &bo);
            unsigned u = map_f(bo);
            if ((u >> 20) == b1) {
                unsigned p = atomicAdd(&lcnt, 1u);
                if (p < LCAP) {
                    lu[p] = u; li[p] = (unsigned)(ebase + v * 4 + j);
                } else {  // overflow fallback (rare): direct global reservation
                    unsigned gp = atomicAdd(&ws[WS_CCNT + row], 1u);
                    if (gp < CAP) { cu[gp] = u; ci[gp] = (unsigned)(ebase + v * 4 + j); }
                }
            }
        }
    }
    __syncthreads();
    unsigned n = lcnt < LCAP ? lcnt : LCAP;
    if (threadIdx.x == 0) gbase = atomicAdd(&ws[WS_CCNT + row], n);
    __syncthreads();
    unsigned gb = gbase;
    for (unsigned i = threadIdx.x; i < n; i += 256) {
        unsigned gp = gb + i;
        if (gp < CAP) { cu[gp] = lu[i]; ci[gp] = li[i]; }
    }
}

// ---------------- Kernel: exact select + stable tie-cut among candidates ----------
__global__ __launch_bounds__(256) void kfinal(unsigned* __restrict__ ws) {
    int row = blockIdx.x;
    unsigned n = ws[WS_CCNT + row];
    if (n > CAP) n = CAP;
    unsigned K = ws[WS_KREM + row];
    const unsigned* cu = ws + CAND_U_OFF + (size_t)row * CAP;
    const unsigned* ci = ws + CAND_I_OFF + (size_t)row * CAP;
    __shared__ unsigned su[CAP];
    __shared__ unsigned hist[256];
    __shared__ unsigned sb[2];
    for (unsigned i = threadIdx.x; i < n; i += 256) su[i] = cu[i];
    __syncthreads();
    unsigned prefix = 0, Kp = K;
    for (int pass = 0; pass < 4; ++pass) {
        int shift = 24 - 8 * pass;
        hist[threadIdx.x] = 0;
        __syncthreads();
        for (unsigned i = threadIdx.x; i < n; i += 256) {
            unsigned u = su[i];
            bool match = (pass == 0) || ((u >> (32 - 8 * pass)) == prefix);
            if (match) atomicAdd(&hist[(u >> shift) & 0xFFu], 1u);
        }
        __syncthreads();
        if (threadIdx.x == 0) {
            unsigned cum = 0, bsel = 0, krem = Kp;
            for (int b = 255; b >= 0; --b) {
                unsigned h = hist[b];
                if (cum + h >= Kp) { bsel = (unsigned)b; krem = Kp - cum; break; }
                cum += h;
            }
            sb[0] = (prefix << 8) | bsel;
            sb[1] = krem;
        }
        __syncthreads();
        prefix = sb[0];
        Kp = sb[1];
        __syncthreads();
    }
    unsigned u_t = prefix, krem2 = Kp;
    // cut = krem2-th smallest original index among candidates equal to u_t
    for (unsigned i = threadIdx.x; i < n; i += 256) {
        if (su[i] == u_t) {
            unsigned myidx = ci[i];
            unsigned r = 0;
            for (unsigned j = 0; j < n; ++j)
                if (su[j] == u_t && ci[j] < myidx) ++r;
            if (r == krem2 - 1) {
                ws[WS_UT + row] = u_t;
                ws[WS_CUT + row] = myidx;
            }
        }
    }
}

// ---------------- Kernel: mark + write both outputs + count active ----------------
__global__ void kmark(const float4* __restrict__ x4, const float4* __restrict__ bt4,
                      const float* __restrict__ bp_p, unsigned* ws,
                      float4* __restrict__ out4, float4* __restrict__ fb4) {
    float gmax = unmap_f(ws[WS_GMAX]);
    float bp = *bp_p;
    unsigned cnt = 0;
    const size_t nvec = (size_t)BR * EC / 4;
    size_t stride = (size_t)gridDim.x * blockDim.x;
    for (size_t v = (size_t)blockIdx.x * blockDim.x + threadIdx.x; v < nvec; v += stride) {
        size_t e0 = v << 2;
        int row = (int)(e0 >> 17);
        int col = (int)(e0 & (size_t)(EC - 1));
        unsigned u_t = ws[WS_UT + row];
        int cut = (int)ws[WS_CUT + row];
        float4 xv = x4[v], bv = bt4[v];
        float xarr[4] = {xv.x, xv.y, xv.z, xv.w};
        float barr[4] = {bv.x, bv.y, bv.z, bv.w};
        float o[4], f[4];
        #pragma unroll
        for (int j = 0; j < 4; ++j) {
            float nb, bo;
            compute_vals(xarr[j], barr[j], gmax, bp, &nb, &bo);
            unsigned u = map_f(bo);
            bool sel = (u > u_t) || ((u == u_t) && ((col + j) <= cut));
            bool saved = sel && (u > 0x80000000u);  // boosted > 0
            o[j] = saved ? 1.0f : 0.0f;
            f[j] = saved ? 0.0f : nb;
            cnt += saved ? 1u : 0u;
        }
        out4[v] = make_float4(o[0], o[1], o[2], o[3]);
        fb4[v] = make_float4(f[0], f[1], f[2], f[3]);
    }
    for (int off = 32; off; off >>= 1) cnt += __shfl_down(cnt, off, 64);
    __shared__ unsigned sc;
    if (threadIdx.x == 0) sc = 0;
    __syncthreads();
    if ((threadIdx.x & 63) == 0) atomicAdd(&sc, cnt);
    __syncthreads();
    if (threadIdx.x == 0) atomicAdd(&ws[WS_ACTIVE], sc);
}

// ---------------- Kernel: compute to_activate ----------------
__global__ void kneed(const float* __restrict__ sp, unsigned* ws) {
    if (threadIdx.x == 0 && blockIdx.x == 0) {
        float min_active = floorf(sp[0] * (float)EC);
        float active = (float)ws[WS_ACTIVE];
        ws[WS_TOACT] = (active < min_active) ? (unsigned)ceilf(min_active - active) : 0u;
    }
}

// ---------------- Correction branch: per-row select on new_boost (gated, dead here) ----
__global__ __launch_bounds__(1024) void kselect_nb(
        const float* __restrict__ x, const float* __restrict__ bt,
        const float* __restrict__ bp_p, unsigned* ws) {
    unsigned K = ws[WS_TOACT];
    if (K == 0) return;
    if (K > EC) K = EC;
    int row = blockIdx.x;
    float gmax = unmap_f(ws[WS_GMAX]);
    float bp = *bp_p;
    const float4* xr4 = (const float4*)(x + (size_t)row * EC);
    const float4* br4 = (const float4*)(bt + (size_t)row * EC);

    __shared__ unsigned hist[256];
    __shared__ unsigned sb[2];

    unsigned prefix = 0;
    unsigned Kp = K;
    for (int pass = 0; pass < 4; ++pass) {
        const int shift = 24 - 8 * pass;
        for (int i = threadIdx.x; i < 256; i += blockDim.x) hist[i] = 0;
        __syncthreads();
        for (int v = threadIdx.x; v < EC / 4; v += blockDim.x) {
            float4 xv = xr4[v];
            float4 bv = br4[v];
            float xs[4] = {xv.x, xv.y, xv.z, xv.w};
            float bs[4] = {bv.x, bv.y, bv.z, bv.w};
            #pragma unroll
            for (int j = 0; j < 4; ++j) {
                float nb, bo;
                compute_vals(xs[j], bs[j], gmax, bp, &nb, &bo);
                unsigned u = map_f(nb);
                bool match = (pass == 0) || ((u >> (32 - 8 * pass)) == prefix);
                if (match) atomicAdd(&hist[(u >> shift) & 0xFFu], 1u);
            }
        }
        __syncthreads();
        if (threadIdx.x == 0) {
            unsigned cum = 0, bsel = 0, krem = Kp;
            for (int b = 255; b >= 0; --b) {
                unsigned h = hist[b];
                if (cum + h >= Kp) { bsel = (unsigned)b; krem = Kp - cum; break; }
                cum += h;
            }
            sb[0] = (prefix << 8) | bsel;
            sb[1] = krem;
        }
        __syncthreads();
        prefix = sb[0];
        Kp = sb[1];
        __syncthreads();
    }
    unsigned u_t = prefix;
    unsigned ties = Kp;

    __shared__ unsigned s_wcnt[16];
    __shared__ unsigned s_run;
    __shared__ int s_cut;
    if (threadIdx.x == 0) { s_run = 0; s_cut = -1; }
    __syncthreads();
    int nw = (int)blockDim.x >> 6;
    int wid = threadIdx.x >> 6, lane = threadIdx.x & 63;
    const float* xs = x + (size_t)row * EC;
    const float* bs = bt + (size_t)row * EC;
    for (int base0 = 0; base0 < EC; base0 += blockDim.x) {
        int i = base0 + threadIdx.x;
        bool eq = false;
        if (i < EC) {
            float nb, bo;
            compute_vals(xs[i], bs[i], gmax, bp, &nb, &bo);
            eq = (map_f(nb) == u_t);
        }
        unsigned long long bal = __ballot(eq);
        if (lane == 0) s_wcnt[wid] = (unsigned)__popcll(bal);
        __syncthreads();
        unsigned run = s_run;
        unsigned wpre = 0;
        for (int w = 0; w < wid; ++w) wpre += s_wcnt[w];
        if (eq) {
            unsigned r = run + wpre + (unsigned)__popcll(bal & ((1ull << lane) - 1ull));
            if (r == ties - 1) s_cut = i;
        }
        __syncthreads();
        if (threadIdx.x == 0) {
            unsigned tot = 0;
            for (int w = 0; w < nw; ++w) tot += s_wcnt[w];
            s_run = run + tot;
        }
        __syncthreads();
        if (s_run >= ties) break;
    }
    if (threadIdx.x == 0) {
        ws[WS_UT2 + row] = u_t;
        ws[WS_CUT2 + row] = (unsigned)s_cut;
    }
}

// ---------------- Correction apply (gated, dead here) ----------------
__global__ void kfix(const float4* __restrict__ x4, const float4* __restrict__ bt4,
                     const float* __restrict__ bp_p, const unsigned* __restrict__ ws,
                     float* __restrict__ out, float* __restrict__ fb) {
    if (ws[WS_TOACT] == 0) return;
    float gmax = unmap_f(ws[WS_GMAX]);
    float bp = *bp_p;
    const size_t nvec = (size_t)BR * EC / 4;
    size_t stride = (size_t)gridDim.x * blockDim.x;
    for (size_t v = (size_t)blockIdx.x * blockDim.x + threadIdx.x; v < nvec; v += stride) {
        size_t e0 = v << 2;
        int row = (int)(e0 >> 17);
        int col = (int)(e0 & (size_t)(EC - 1));
        unsigned u_t = ws[WS_UT2 + row];
        int cut = (int)ws[WS_CUT2 + row];
        float4 xv = x4[v], bv = bt4[v];
        float xarr[4] = {xv.x, xv.y, xv.z, xv.w};
        float barr[4] = {bv.x, bv.y, bv.z, bv.w};
        #pragma unroll
        for (int j = 0; j < 4; ++j) {
            float nb, bo;
            compute_vals(xarr[j], barr[j], gmax, bp, &nb, &bo);
            unsigned u = map_f(nb);
            if (u > u_t || (u == u_t && (col + j) <= cut)) {
                out[e0 + j] = 1.0f;
                fb[e0 + j] = 0.0f;
            }
        }
    }
}

extern "C" void kernel_launch(void* const* d_in, const int* in_sizes, int n_in,
                              void* d_out, int out_size, void* d_ws, size_t ws_size,
                              hipStream_t stream) {
    const float* x  = (const float*)d_in[0];
    const float* bt = (const float*)d_in[1];
    const float* sp = (const float*)d_in[2];
    const float* bp = (const float*)d_in[3];
    float* out = (float*)d_out;
    float* fb  = out + (size_t)BR * EC;
    unsigned* ws = (unsigned*)d_ws;

    hipMemsetAsync(d_ws, 0, ZERO_BYTES, stream);

    kmax<<<1024, 256, 0, stream>>>((const float4*)x, ws, BR * EC / 4);
    khist<<<BR * CHUNKS, 256, 0, stream>>>((const float4*)x, (const float4*)bt, bp, ws);
    kfind<<<BR, 256, 0, stream>>>(sp, ws);
    kcollect<<<BR * CHUNKS, 256, 0, stream>>>((const float4*)x, (const float4*)bt, bp, ws);
    kfinal<<<BR, 256, 0, stream>>>(ws);
    kmark<<<2048, 256, 0, stream>>>((const float4*)x, (const float4*)bt, bp, ws,
                                    (float4*)out, (float4*)fb);
    kneed<<<1, 64, 0, stream>>>(sp, ws);
    kselect_nb<<<BR, 1024, 0, stream>>>(x, bt, bp, ws);
    kfix<<<2048, 256, 0, stream>>>((const float4*)x, (const float4*)bt, bp, ws, out, fb);
}

// Round 4
// 137.697 us; speedup vs baseline: 3.7796x; 1.5751x over previous
//
#include <hip/hip_runtime.h>

#define BR 64
#define EC 131072
#define BINS 4096
#define CAP 4096
#define LCAP 1024
#define CHUNKS 16
#define CHUNK_V (EC / CHUNKS / 4)   // float4 per chunk = 2048

// ws word-offset layout
#define WS_GMAX 0
#define WS_ACTIVE 1
#define WS_TOACT 2
#define WS_B1 8        // +row
#define WS_KREM 72     // +row
#define WS_UT 136      // +row
#define WS_CUT 200     // +row
#define WS_CCNT 264    // +row
#define WS_UT2 512     // +row (correction branch)
#define WS_CUT2 576    // +row
#define HIST_OFF 1024
#define CAND_U_OFF (HIST_OFF + BR * BINS)
#define CAND_I_OFF (CAND_U_OFF + BR * CAP)
#define ZERO_BYTES ((size_t)CAND_U_OFF * 4)   // scalars + per-row slots + histograms

// Monotonic float->uint mapping (order-preserving, bijective)
__device__ __forceinline__ unsigned map_f(float f) {
    unsigned b = __float_as_uint(f);
    return (b & 0x80000000u) ? ~b : (b | 0x80000000u);
}
__device__ __forceinline__ float unmap_f(unsigned u) {
    unsigned b = (u & 0x80000000u) ? (u & 0x7FFFFFFFu) : ~u;
    return __uint_as_float(b);
}

// EXACT numpy-op-sequence value computation; contract(off) so every kernel
// computes bit-identical values.
__device__ __forceinline__ void compute_vals(float x, float bt, float gmax, float bp,
                                             float* nb, float* bo) {
#pragma clang fp contract(off)
    float q = x / gmax;
    float t = 1.0f - q;
    float p = t * bp;
    float nbv = bt + p;
    *nb = nbv;
    *bo = fmaxf(x, 0.0f) + nbv;
}

__device__ __forceinline__ unsigned umax_(unsigned a, unsigned b) { return a > b ? a : b; }

// ---------------- Kernel: global max of x ----------------
__global__ void kmax(const float4* __restrict__ x4, unsigned* ws, int nvec) {
    unsigned m = 0;
    int stride = gridDim.x * blockDim.x;
    for (int v = blockIdx.x * blockDim.x + threadIdx.x; v < nvec; v += stride) {
        float4 xv = x4[v];
        m = umax_(m, map_f(xv.x)); m = umax_(m, map_f(xv.y));
        m = umax_(m, map_f(xv.z)); m = umax_(m, map_f(xv.w));
    }
    for (int off = 32; off; off >>= 1) m = umax_(m, __shfl_down(m, off, 64));
    __shared__ unsigned sm[16];
    int wid = threadIdx.x >> 6, lane = threadIdx.x & 63;
    if (lane == 0) sm[wid] = m;
    __syncthreads();
    if (threadIdx.x == 0) {
        unsigned mm = sm[0];
        int nw = blockDim.x >> 6;
        for (int w = 1; w < nw; ++w) mm = umax_(mm, sm[w]);
        atomicMax(ws, mm);
    }
}

// ---------------- Kernel: per-row 4096-bin histogram of top-12 bits ----------------
__global__ __launch_bounds__(256) void khist(const float4* __restrict__ x4,
                                             const float4* __restrict__ bt4,
                                             const float* __restrict__ bp_p,
                                             unsigned* __restrict__ ws) {
    __shared__ unsigned h[2][BINS];
    for (int i = threadIdx.x; i < 2 * BINS; i += 256) h[0][i] = 0;
    int row = blockIdx.x >> 4;
    int chunk = blockIdx.x & (CHUNKS - 1);
    int cpy = threadIdx.x >> 7;   // wave-pair id
    float gmax = unmap_f(ws[WS_GMAX]);
    float bp = *bp_p;
    size_t base = (size_t)row * (EC / 4) + (size_t)chunk * CHUNK_V;
    __syncthreads();
    for (int v = threadIdx.x; v < CHUNK_V; v += 256) {
        float4 xv = x4[base + v];
        float4 bv = bt4[base + v];
        float xs[4] = {xv.x, xv.y, xv.z, xv.w};
        float bs[4] = {bv.x, bv.y, bv.z, bv.w};
        #pragma unroll
        for (int j = 0; j < 4; ++j) {
            float nb, bo;
            compute_vals(xs[j], bs[j], gmax, bp, &nb, &bo);
            atomicAdd(&h[cpy][map_f(bo) >> 20], 1u);
        }
    }
    __syncthreads();
    unsigned* gh = ws + HIST_OFF + (size_t)row * BINS;
    int rot = chunk * 256;
    for (int i0 = threadIdx.x; i0 < BINS; i0 += 256) {
        int i = (i0 + rot) & (BINS - 1);
        unsigned v = h[0][i] + h[1][i];
        if (v) atomicAdd(&gh[i], v);   // fire-and-forget
    }
}

// ---------------- Kernel: find bin containing K-th largest, per row ----------------
__global__ __launch_bounds__(256) void kfind(const float* __restrict__ sp,
                                             unsigned* __restrict__ ws) {
    int row = blockIdx.x;
    unsigned K = (unsigned)ceilf(sp[1] * (float)EC);
    if (K > EC) K = EC;
    if (K == 0) K = 1;
    const unsigned* gh = ws + HIST_OFF + (size_t)row * BINS;
    __shared__ unsigned ssum[256];
    __shared__ unsigned sabove[256];
    int t = threadIdx.x;
    unsigned hv[16];
    unsigned s = 0;
    #pragma unroll
    for (int j = 0; j < 16; ++j) { hv[j] = gh[t * 16 + j]; s += hv[j]; }
    ssum[t] = s;
    __syncthreads();
    if (t == 0) {
        unsigned acc = 0;
        for (int q = 255; q >= 0; --q) { sabove[q] = acc; acc += ssum[q]; }
    }
    __syncthreads();
    unsigned cum = sabove[t];
    for (int j = 15; j >= 0; --j) {
        unsigned h = hv[j];
        if (cum < K && cum + h >= K) {
            ws[WS_B1 + row] = (unsigned)(t * 16 + j);
            ws[WS_KREM + row] = K - cum;
        }
        cum += h;
    }
}

// ---------------- Kernel: collect candidates (block-aggregated reservation) -------
__global__ __launch_bounds__(256) void kcollect(const float4* __restrict__ x4,
                                                const float4* __restrict__ bt4,
                                                const float* __restrict__ bp_p,
                                                unsigned* __restrict__ ws) {
    __shared__ unsigned lu[LCAP], li[LCAP];
    __shared__ unsigned lcnt, gbase;
    if (threadIdx.x == 0) lcnt = 0;
    int row = blockIdx.x >> 4;
    int chunk = blockIdx.x & (CHUNKS - 1);
    unsigned b1 = ws[WS_B1 + row];
    float gmax = unmap_f(ws[WS_GMAX]);
    float bp = *bp_p;
    unsigned* cu = ws + CAND_U_OFF + (size_t)row * CAP;
    unsigned* ci = ws + CAND_I_OFF + (size_t)row * CAP;
    size_t base = (size_t)row * (EC / 4) + (size_t)chunk * CHUNK_V;
    int ebase = chunk * (EC / CHUNKS);
    __syncthreads();
    for (int v = threadIdx.x; v < CHUNK_V; v += 256) {
        float4 xv = x4[base + v];
        float4 bv = bt4[base + v];
        float xs[4] = {xv.x, xv.y, xv.z, xv.w};
        float bs[4] = {bv.x, bv.y, bv.z, bv.w};
        #pragma unroll
        for (int j = 0; j < 4; ++j) {
            float nb, bo;
            compute_vals(xs[j], bs[j], gmax, bp, &nb, &bo);
            unsigned u = map_f(bo);
            if ((u >> 20) == b1) {
                unsigned p = atomicAdd(&lcnt, 1u);
                if (p < LCAP) {
                    lu[p] = u; li[p] = (unsigned)(ebase + v * 4 + j);
                } else {  // overflow fallback (rare)
                    unsigned gp = atomicAdd(&ws[WS_CCNT + row], 1u);
                    if (gp < CAP) { cu[gp] = u; ci[gp] = (unsigned)(ebase + v * 4 + j); }
                }
            }
        }
    }
    __syncthreads();
    unsigned n = lcnt < LCAP ? lcnt : LCAP;
    if (threadIdx.x == 0) gbase = atomicAdd(&ws[WS_CCNT + row], n);
    __syncthreads();
    unsigned gb = gbase;
    for (unsigned i = threadIdx.x; i < n; i += 256) {
        unsigned gp = gb + i;
        if (gp < CAP) { cu[gp] = lu[i]; ci[gp] = li[i]; }
    }
}

// ---------------- Kernel: exact select + stable tie-cut among candidates ----------
// ALL candidate data staged in LDS; parallel suffix scan per radix pass.
__global__ __launch_bounds__(256) void kfinal(unsigned* __restrict__ ws) {
    int row = blockIdx.x;
    unsigned n = ws[WS_CCNT + row];
    if (n > CAP) n = CAP;
    unsigned K = ws[WS_KREM + row];
    const unsigned* cu = ws + CAND_U_OFF + (size_t)row * CAP;
    const unsigned* ci = ws + CAND_I_OFF + (size_t)row * CAP;
    __shared__ unsigned su[CAP];
    __shared__ unsigned si[CAP];
    __shared__ unsigned hist[256];
    __shared__ unsigned scan[256];
    __shared__ unsigned sb[2];
    for (unsigned i = threadIdx.x; i < n; i += 256) { su[i] = cu[i]; si[i] = ci[i]; }
    __syncthreads();
    int t = threadIdx.x;
    unsigned prefix = 0, Kp = K;
    for (int pass = 0; pass < 4; ++pass) {
        int shift = 24 - 8 * pass;
        hist[t] = 0;
        __syncthreads();
        for (unsigned i = t; i < n; i += 256) {
            unsigned u = su[i];
            bool match = (pass == 0) || ((u >> (32 - 8 * pass)) == prefix);
            if (match) atomicAdd(&hist[(u >> shift) & 0xFFu], 1u);
        }
        __syncthreads();
        // parallel inclusive suffix scan of hist -> scan[t] = sum_{b>=t} hist[b]
        unsigned my = hist[t];
        scan[t] = my;
        __syncthreads();
        for (int off = 1; off < 256; off <<= 1) {
            unsigned v = (t + off < 256) ? scan[t + off] : 0u;
            __syncthreads();
            scan[t] += v;
            __syncthreads();
        }
        unsigned incl = scan[t], excl = incl - my;
        if (excl < Kp && incl >= Kp) {
            sb[0] = (prefix << 8) | (unsigned)t;
            sb[1] = Kp - excl;
        }
        __syncthreads();
        prefix = sb[0];
        Kp = sb[1];
        __syncthreads();
    }
    unsigned u_t = prefix, krem2 = Kp;
    // cut = krem2-th smallest original index among candidates equal to u_t (all LDS)
    for (unsigned i = t; i < n; i += 256) {
        if (su[i] == u_t) {
            unsigned myidx = si[i];
            unsigned r = 0;
            for (unsigned j = 0; j < n; ++j)
                if (su[j] == u_t && si[j] < myidx) ++r;
            if (r == krem2 - 1) {
                ws[WS_UT + row] = u_t;
                ws[WS_CUT + row] = myidx;
            }
        }
    }
}

// ---------------- Kernel: mark + write both outputs + count active ----------------
__global__ void kmark(const float4* __restrict__ x4, const float4* __restrict__ bt4,
                      const float* __restrict__ bp_p, unsigned* ws,
                      float4* __restrict__ out4, float4* __restrict__ fb4) {
    float gmax = unmap_f(ws[WS_GMAX]);
    float bp = *bp_p;
    unsigned cnt = 0;
    const size_t nvec = (size_t)BR * EC / 4;
    size_t stride = (size_t)gridDim.x * blockDim.x;
    for (size_t v = (size_t)blockIdx.x * blockDim.x + threadIdx.x; v < nvec; v += stride) {
        size_t e0 = v << 2;
        int row = (int)(e0 >> 17);
        int col = (int)(e0 & (size_t)(EC - 1));
        unsigned u_t = ws[WS_UT + row];
        int cut = (int)ws[WS_CUT + row];
        float4 xv = x4[v], bv = bt4[v];
        float xarr[4] = {xv.x, xv.y, xv.z, xv.w};
        float barr[4] = {bv.x, bv.y, bv.z, bv.w};
        float o[4], f[4];
        #pragma unroll
        for (int j = 0; j < 4; ++j) {
            float nb, bo;
            compute_vals(xarr[j], barr[j], gmax, bp, &nb, &bo);
            unsigned u = map_f(bo);
            bool sel = (u > u_t) || ((u == u_t) && ((col + j) <= cut));
            bool saved = sel && (u > 0x80000000u);  // boosted > 0
            o[j] = saved ? 1.0f : 0.0f;
            f[j] = saved ? 0.0f : nb;
            cnt += saved ? 1u : 0u;
        }
        out4[v] = make_float4(o[0], o[1], o[2], o[3]);
        fb4[v] = make_float4(f[0], f[1], f[2], f[3]);
    }
    for (int off = 32; off; off >>= 1) cnt += __shfl_down(cnt, off, 64);
    __shared__ unsigned sc;
    if (threadIdx.x == 0) sc = 0;
    __syncthreads();
    if ((threadIdx.x & 63) == 0) atomicAdd(&sc, cnt);
    __syncthreads();
    if (threadIdx.x == 0) atomicAdd(&ws[WS_ACTIVE], sc);
}

// ---------------- Kernel: compute to_activate ----------------
__global__ void kneed(const float* __restrict__ sp, unsigned* ws) {
    if (threadIdx.x == 0 && blockIdx.x == 0) {
        float min_active = floorf(sp[0] * (float)EC);
        float active = (float)ws[WS_ACTIVE];
        ws[WS_TOACT] = (active < min_active) ? (unsigned)ceilf(min_active - active) : 0u;
    }
}

// ---------------- Correction branch: per-row select on new_boost (gated, dead here) ----
__global__ __launch_bounds__(1024) void kselect_nb(
        const float* __restrict__ x, const float* __restrict__ bt,
        const float* __restrict__ bp_p, unsigned* ws) {
    unsigned K = ws[WS_TOACT];
    if (K == 0) return;
    if (K > EC) K = EC;
    int row = blockIdx.x;
    float gmax = unmap_f(ws[WS_GMAX]);
    float bp = *bp_p;
    const float4* xr4 = (const float4*)(x + (size_t)row * EC);
    const float4* br4 = (const float4*)(bt + (size_t)row * EC);

    __shared__ unsigned hist[256];
    __shared__ unsigned sb[2];

    unsigned prefix = 0;
    unsigned Kp = K;
    for (int pass = 0; pass < 4; ++pass) {
        const int shift = 24 - 8 * pass;
        for (int i = threadIdx.x; i < 256; i += blockDim.x) hist[i] = 0;
        __syncthreads();
        for (int v = threadIdx.x; v < EC / 4; v += blockDim.x) {
            float4 xv = xr4[v];
            float4 bv = br4[v];
            float xs[4] = {xv.x, xv.y, xv.z, xv.w};
            float bs[4] = {bv.x, bv.y, bv.z, bv.w};
            #pragma unroll
            for (int j = 0; j < 4; ++j) {
                float nb, bo;
                compute_vals(xs[j], bs[j], gmax, bp, &nb, &bo);
                unsigned u = map_f(nb);
                bool match = (pass == 0) || ((u >> (32 - 8 * pass)) == prefix);
                if (match) atomicAdd(&hist[(u >> shift) & 0xFFu], 1u);
            }
        }
        __syncthreads();
        if (threadIdx.x == 0) {
            unsigned cum = 0, bsel = 0, krem = Kp;
            for (int b = 255; b >= 0; --b) {
                unsigned h = hist[b];
                if (cum + h >= Kp) { bsel = (unsigned)b; krem = Kp - cum; break; }
                cum += h;
            }
            sb[0] = (prefix << 8) | bsel;
            sb[1] = krem;
        }
        __syncthreads();
        prefix = sb[0];
        Kp = sb[1];
        __syncthreads();
    }
    unsigned u_t = prefix;
    unsigned ties = Kp;

    __shared__ unsigned s_wcnt[16];
    __shared__ unsigned s_run;
    __shared__ int s_cut;
    if (threadIdx.x == 0) { s_run = 0; s_cut = -1; }
    __syncthreads();
    int nw = (int)blockDim.x >> 6;
    int wid = threadIdx.x >> 6, lane = threadIdx.x & 63;
    const float* xs = x + (size_t)row * EC;
    const float* bs = bt + (size_t)row * EC;
    for (int base0 = 0; base0 < EC; base0 += blockDim.x) {
        int i = base0 + threadIdx.x;
        bool eq = false;
        if (i < EC) {
            float nb, bo;
            compute_vals(xs[i], bs[i], gmax, bp, &nb, &bo);
            eq = (map_f(nb) == u_t);
        }
        unsigned long long bal = __ballot(eq);
        if (lane == 0) s_wcnt[wid] = (unsigned)__popcll(bal);
        __syncthreads();
        unsigned run = s_run;
        unsigned wpre = 0;
        for (int w = 0; w < wid; ++w) wpre += s_wcnt[w];
        if (eq) {
            unsigned r = run + wpre + (unsigned)__popcll(bal & ((1ull << lane) - 1ull));
            if (r == ties - 1) s_cut = i;
        }
        __syncthreads();
        if (threadIdx.x == 0) {
            unsigned tot = 0;
            for (int w = 0; w < nw; ++w) tot += s_wcnt[w];
            s_run = run + tot;
        }
        __syncthreads();
        if (s_run >= ties) break;
    }
    if (threadIdx.x == 0) {
        ws[WS_UT2 + row] = u_t;
        ws[WS_CUT2 + row] = (unsigned)s_cut;
    }
}

// ---------------- Correction apply (gated, dead here) ----------------
__global__ void kfix(const float4* __restrict__ x4, const float4* __restrict__ bt4,
                     const float* __restrict__ bp_p, const unsigned* __restrict__ ws,
                     float* __restrict__ out, float* __restrict__ fb) {
    if (ws[WS_TOACT] == 0) return;
    float gmax = unmap_f(ws[WS_GMAX]);
    float bp = *bp_p;
    const size_t nvec = (size_t)BR * EC / 4;
    size_t stride = (size_t)gridDim.x * blockDim.x;
    for (size_t v = (size_t)blockIdx.x * blockDim.x + threadIdx.x; v < nvec; v += stride) {
        size_t e0 = v << 2;
        int row = (int)(e0 >> 17);
        int col = (int)(e0 & (size_t)(EC - 1));
        unsigned u_t = ws[WS_UT2 + row];
        int cut = (int)ws[WS_CUT2 + row];
        float4 xv = x4[v], bv = bt4[v];
        float xarr[4] = {xv.x, xv.y, xv.z, xv.w};
        float barr[4] = {bv.x, bv.y, bv.z, bv.w};
        #pragma unroll
        for (int j = 0; j < 4; ++j) {
            float nb, bo;
            compute_vals(xarr[j], barr[j], gmax, bp, &nb, &bo);
            unsigned u = map_f(nb);
            if (u > u_t || (u == u_t && (col + j) <= cut)) {
                out[e0 + j] = 1.0f;
                fb[e0 + j] = 0.0f;
            }
        }
    }
}

extern "C" void kernel_launch(void* const* d_in, const int* in_sizes, int n_in,
                              void* d_out, int out_size, void* d_ws, size_t ws_size,
                              hipStream_t stream) {
    const float* x  = (const float*)d_in[0];
    const float* bt = (const float*)d_in[1];
    const float* sp = (const float*)d_in[2];
    const float* bp = (const float*)d_in[3];
    float* out = (float*)d_out;
    float* fb  = out + (size_t)BR * EC;
    unsigned* ws = (unsigned*)d_ws;

    hipMemsetAsync(d_ws, 0, ZERO_BYTES, stream);

    kmax<<<1024, 256, 0, stream>>>((const float4*)x, ws, BR * EC / 4);
    khist<<<BR * CHUNKS, 256, 0, stream>>>((const float4*)x, (const float4*)bt, bp, ws);
    kfind<<<BR, 256, 0, stream>>>(sp, ws);
    kcollect<<<BR * CHUNKS, 256, 0, stream>>>((const float4*)x, (const float4*)bt, bp, ws);
    kfinal<<<BR, 256, 0, stream>>>(ws);
    kmark<<<2048, 256, 0, stream>>>((const float4*)x, (const float4*)bt, bp, ws,
                                    (float4*)out, (float4*)fb);
    kneed<<<1, 64, 0, stream>>>(sp, ws);
    kselect_nb<<<BR, 1024, 0, stream>>>(x, bt, bp, ws);
    kfix<<<2048, 256, 0, stream>>>((const float4*)x, (const float4*)bt, bp, ws, out, fb);
}

// Round 5
// 107.435 us; speedup vs baseline: 4.8442x; 1.2817x over previous
//
#include <hip/hip_runtime.h>

#define BR 64
#define EC 131072
#define BINS 4096
#define CAP 4096
#define LCAP 1024
#define CHUNKS 16
#define CHUNK_V (EC / CHUNKS / 4)   // float4 per chunk = 2048

// ws word-offset layout
#define WS_GMAX 0
#define WS_ACTIVE 1
#define WS_TOACT 2
#define WS_B1 8        // +row
#define WS_KREM 72     // +row
#define WS_UT 136      // +row
#define WS_CUT 200     // +row
#define WS_CCNT 264    // +row
#define WS_UT2 512     // +row (correction branch)
#define WS_CUT2 576    // +row
#define HIST_OFF 1024
#define CAND_U_OFF (HIST_OFF + BR * BINS)
#define CAND_I_OFF (CAND_U_OFF + BR * CAP)
#define ZERO_BYTES ((size_t)CAND_U_OFF * 4)   // scalars + per-row slots + histograms

// Monotonic float->uint mapping (order-preserving, bijective)
__device__ __forceinline__ unsigned map_f(float f) {
    unsigned b = __float_as_uint(f);
    return (b & 0x80000000u) ? ~b : (b | 0x80000000u);
}
__device__ __forceinline__ float unmap_f(unsigned u) {
    unsigned b = (u & 0x80000000u) ? (u & 0x7FFFFFFFu) : ~u;
    return __uint_as_float(b);
}

// EXACT numpy-op-sequence value computation; contract(off) so every kernel
// computes bit-identical values.
__device__ __forceinline__ void compute_vals(float x, float bt, float gmax, float bp,
                                             float* nb, float* bo) {
#pragma clang fp contract(off)
    float q = x / gmax;
    float t = 1.0f - q;
    float p = t * bp;
    float nbv = bt + p;
    *nb = nbv;
    *bo = fmaxf(x, 0.0f) + nbv;
}

__device__ __forceinline__ unsigned umax_(unsigned a, unsigned b) { return a > b ? a : b; }

// ---------------- Kernel: global max of x ----------------
__global__ void kmax(const float4* __restrict__ x4, unsigned* ws, int nvec) {
    unsigned m = 0;
    int stride = gridDim.x * blockDim.x;
    for (int v = blockIdx.x * blockDim.x + threadIdx.x; v < nvec; v += stride) {
        float4 xv = x4[v];
        m = umax_(m, map_f(xv.x)); m = umax_(m, map_f(xv.y));
        m = umax_(m, map_f(xv.z)); m = umax_(m, map_f(xv.w));
    }
    for (int off = 32; off; off >>= 1) m = umax_(m, __shfl_down(m, off, 64));
    __shared__ unsigned sm[16];
    int wid = threadIdx.x >> 6, lane = threadIdx.x & 63;
    if (lane == 0) sm[wid] = m;
    __syncthreads();
    if (threadIdx.x == 0) {
        unsigned mm = sm[0];
        int nw = blockDim.x >> 6;
        for (int w = 1; w < nw; ++w) mm = umax_(mm, sm[w]);
        atomicMax(ws, mm);
    }
}

// ---------------- Kernel: per-row 4096-bin histogram of top-12 bits ----------------
__global__ __launch_bounds__(256) void khist(const float4* __restrict__ x4,
                                             const float4* __restrict__ bt4,
                                             const float* __restrict__ bp_p,
                                             unsigned* __restrict__ ws) {
    __shared__ unsigned h[2][BINS];
    for (int i = threadIdx.x; i < 2 * BINS; i += 256) h[0][i] = 0;
    int row = blockIdx.x >> 4;
    int chunk = blockIdx.x & (CHUNKS - 1);
    int cpy = threadIdx.x >> 7;   // wave-pair id
    float gmax = unmap_f(ws[WS_GMAX]);
    float bp = *bp_p;
    size_t base = (size_t)row * (EC / 4) + (size_t)chunk * CHUNK_V;
    __syncthreads();
    for (int v = threadIdx.x; v < CHUNK_V; v += 256) {
        float4 xv = x4[base + v];
        float4 bv = bt4[base + v];
        float xs[4] = {xv.x, xv.y, xv.z, xv.w};
        float bs[4] = {bv.x, bv.y, bv.z, bv.w};
        #pragma unroll
        for (int j = 0; j < 4; ++j) {
            float nb, bo;
            compute_vals(xs[j], bs[j], gmax, bp, &nb, &bo);
            atomicAdd(&h[cpy][map_f(bo) >> 20], 1u);
        }
    }
    __syncthreads();
    unsigned* gh = ws + HIST_OFF + (size_t)row * BINS;
    int rot = chunk * 256;
    for (int i0 = threadIdx.x; i0 < BINS; i0 += 256) {
        int i = (i0 + rot) & (BINS - 1);
        unsigned v = h[0][i] + h[1][i];
        if (v) atomicAdd(&gh[i], v);   // fire-and-forget
    }
}

// ---------------- Kernel: find bin containing K-th largest, per row ----------------
__global__ __launch_bounds__(256) void kfind(const float* __restrict__ sp,
                                             unsigned* __restrict__ ws) {
    int row = blockIdx.x;
    unsigned K = (unsigned)ceilf(sp[1] * (float)EC);
    if (K > EC) K = EC;
    if (K == 0) K = 1;
    const unsigned* gh = ws + HIST_OFF + (size_t)row * BINS;
    __shared__ unsigned ssum[256];
    __shared__ unsigned sabove[256];
    int t = threadIdx.x;
    unsigned hv[16];
    unsigned s = 0;
    #pragma unroll
    for (int j = 0; j < 16; ++j) { hv[j] = gh[t * 16 + j]; s += hv[j]; }
    ssum[t] = s;
    __syncthreads();
    if (t == 0) {
        unsigned acc = 0;
        for (int q = 255; q >= 0; --q) { sabove[q] = acc; acc += ssum[q]; }
    }
    __syncthreads();
    unsigned cum = sabove[t];
    for (int j = 15; j >= 0; --j) {
        unsigned h = hv[j];
        if (cum < K && cum + h >= K) {
            ws[WS_B1 + row] = (unsigned)(t * 16 + j);
            ws[WS_KREM + row] = K - cum;
        }
        cum += h;
    }
}

// ---------------- Kernel: collect candidates (block-aggregated reservation) -------
__global__ __launch_bounds__(256) void kcollect(const float4* __restrict__ x4,
                                                const float4* __restrict__ bt4,
                                                const float* __restrict__ bp_p,
                                                unsigned* __restrict__ ws) {
    __shared__ unsigned lu[LCAP], li[LCAP];
    __shared__ unsigned lcnt, gbase;
    if (threadIdx.x == 0) lcnt = 0;
    int row = blockIdx.x >> 4;
    int chunk = blockIdx.x & (CHUNKS - 1);
    unsigned b1 = ws[WS_B1 + row];
    float gmax = unmap_f(ws[WS_GMAX]);
    float bp = *bp_p;
    unsigned* cu = ws + CAND_U_OFF + (size_t)row * CAP;
    unsigned* ci = ws + CAND_I_OFF + (size_t)row * CAP;
    size_t base = (size_t)row * (EC / 4) + (size_t)chunk * CHUNK_V;
    int ebase = chunk * (EC / CHUNKS);
    __syncthreads();
    for (int v = threadIdx.x; v < CHUNK_V; v += 256) {
        float4 xv = x4[base + v];
        float4 bv = bt4[base + v];
        float xs[4] = {xv.x, xv.y, xv.z, xv.w};
        float bs[4] = {bv.x, bv.y, bv.z, bv.w};
        #pragma unroll
        for (int j = 0; j < 4; ++j) {
            float nb, bo;
            compute_vals(xs[j], bs[j], gmax, bp, &nb, &bo);
            unsigned u = map_f(bo);
            if ((u >> 20) == b1) {
                unsigned p = atomicAdd(&lcnt, 1u);
                if (p < LCAP) {
                    lu[p] = u; li[p] = (unsigned)(ebase + v * 4 + j);
                } else {  // overflow fallback (rare)
                    unsigned gp = atomicAdd(&ws[WS_CCNT + row], 1u);
                    if (gp < CAP) { cu[gp] = u; ci[gp] = (unsigned)(ebase + v * 4 + j); }
                }
            }
        }
    }
    __syncthreads();
    unsigned n = lcnt < LCAP ? lcnt : LCAP;
    if (threadIdx.x == 0) gbase = atomicAdd(&ws[WS_CCNT + row], n);
    __syncthreads();
    unsigned gb = gbase;
    for (unsigned i = threadIdx.x; i < n; i += 256) {
        unsigned gp = gb + i;
        if (gp < CAP) { cu[gp] = lu[i]; ci[gp] = li[i]; }
    }
}

// ---------------- Kernel: exact select + stable tie-cut among candidates ----------
// Radix only over the low 20 bits (top 12 known = b1); fully parallel tie-cut.
__global__ __launch_bounds__(256) void kfinal(unsigned* __restrict__ ws) {
    int row = blockIdx.x;
    unsigned n = ws[WS_CCNT + row];
    if (n > CAP) n = CAP;
    unsigned b1 = ws[WS_B1 + row];
    unsigned K = ws[WS_KREM + row];   // rank of target within this bin
    const unsigned* cu = ws + CAND_U_OFF + (size_t)row * CAP;
    const unsigned* ci = ws + CAND_I_OFF + (size_t)row * CAP;
    __shared__ unsigned su[CAP];
    __shared__ unsigned marr[CAP];
    __shared__ unsigned hist[256];
    __shared__ unsigned scan[256];
    __shared__ unsigned sb[2];
    __shared__ unsigned mcnt;
    for (unsigned i = threadIdx.x; i < n; i += 256) su[i] = cu[i];
    if (threadIdx.x == 0) mcnt = 0;
    __syncthreads();
    int t = threadIdx.x;

    unsigned pv = b1 << 20;   // value bits fixed so far
    unsigned Kp = K;
    const int shifts[3] = {12, 4, 0};
    const unsigned wmask[3] = {0xFFu, 0xFFu, 0xFu};
    const unsigned pmask[3] = {0xFFF00000u, 0xFFFFF000u, 0xFFFFFFF0u};
    for (int pass = 0; pass < 3; ++pass) {
        int shift = shifts[pass];
        unsigned msk = wmask[pass];
        hist[t] = 0;
        __syncthreads();
        for (unsigned i = t; i < n; i += 256) {
            unsigned u = su[i];
            if ((u & pmask[pass]) == pv) atomicAdd(&hist[(u >> shift) & msk], 1u);
        }
        __syncthreads();
        // parallel inclusive suffix scan: scan[t] = sum_{b>=t} hist[b]
        unsigned my = hist[t];
        scan[t] = my;
        __syncthreads();
        for (int off = 1; off < 256; off <<= 1) {
            unsigned v = (t + off < 256) ? scan[t + off] : 0u;
            __syncthreads();
            scan[t] += v;
            __syncthreads();
        }
        unsigned incl = scan[t], excl = incl - my;
        if ((unsigned)t <= msk && excl < Kp && incl >= Kp) {
            sb[0] = pv | ((unsigned)t << shift);
            sb[1] = Kp - excl;
        }
        __syncthreads();
        pv = sb[0];
        Kp = sb[1];
        __syncthreads();
    }
    unsigned u_t = pv, krem2 = Kp;

    // compact matching candidates' original indices (typically 1 match)
    for (unsigned i = t; i < n; i += 256)
        if (su[i] == u_t) { unsigned p = atomicAdd(&mcnt, 1u); if (p < CAP) marr[p] = ci[i]; }
    __syncthreads();
    unsigned m = mcnt < CAP ? mcnt : CAP;
    // parallel rank among matches: cut = index with exactly krem2-1 smaller indices
    for (unsigned i = t; i < m; i += 256) {
        unsigned myidx = marr[i];
        unsigned r = 0;
        for (unsigned j = 0; j < m; ++j) r += (marr[j] < myidx) ? 1u : 0u;
        if (r == krem2 - 1) {
            ws[WS_UT + row] = u_t;
            ws[WS_CUT + row] = myidx;
        }
    }
}

// ---------------- Kernel: mark + write both outputs + count active ----------------
__global__ void kmark(const float4* __restrict__ x4, const float4* __restrict__ bt4,
                      const float* __restrict__ bp_p, unsigned* ws,
                      float4* __restrict__ out4, float4* __restrict__ fb4) {
    float gmax = unmap_f(ws[WS_GMAX]);
    float bp = *bp_p;
    unsigned cnt = 0;
    const size_t nvec = (size_t)BR * EC / 4;
    size_t stride = (size_t)gridDim.x * blockDim.x;
    for (size_t v = (size_t)blockIdx.x * blockDim.x + threadIdx.x; v < nvec; v += stride) {
        size_t e0 = v << 2;
        int row = (int)(e0 >> 17);
        int col = (int)(e0 & (size_t)(EC - 1));
        unsigned u_t = ws[WS_UT + row];
        int cut = (int)ws[WS_CUT + row];
        float4 xv = x4[v], bv = bt4[v];
        float xarr[4] = {xv.x, xv.y, xv.z, xv.w};
        float barr[4] = {bv.x, bv.y, bv.z, bv.w};
        float o[4], f[4];
        #pragma unroll
        for (int j = 0; j < 4; ++j) {
            float nb, bo;
            compute_vals(xarr[j], barr[j], gmax, bp, &nb, &bo);
            unsigned u = map_f(bo);
            bool sel = (u > u_t) || ((u == u_t) && ((col + j) <= cut));
            bool saved = sel && (u > 0x80000000u);  // boosted > 0
            o[j] = saved ? 1.0f : 0.0f;
            f[j] = saved ? 0.0f : nb;
            cnt += saved ? 1u : 0u;
        }
        out4[v] = make_float4(o[0], o[1], o[2], o[3]);
        fb4[v] = make_float4(f[0], f[1], f[2], f[3]);
    }
    for (int off = 32; off; off >>= 1) cnt += __shfl_down(cnt, off, 64);
    __shared__ unsigned sc;
    if (threadIdx.x == 0) sc = 0;
    __syncthreads();
    if ((threadIdx.x & 63) == 0) atomicAdd(&sc, cnt);
    __syncthreads();
    if (threadIdx.x == 0) atomicAdd(&ws[WS_ACTIVE], sc);
}

// ---------------- Kernel: compute to_activate ----------------
__global__ void kneed(const float* __restrict__ sp, unsigned* ws) {
    if (threadIdx.x == 0 && blockIdx.x == 0) {
        float min_active = floorf(sp[0] * (float)EC);
        float active = (float)ws[WS_ACTIVE];
        ws[WS_TOACT] = (active < min_active) ? (unsigned)ceilf(min_active - active) : 0u;
    }
}

// ---------------- Correction branch: per-row select on new_boost (gated, dead here) ----
__global__ __launch_bounds__(1024) void kselect_nb(
        const float* __restrict__ x, const float* __restrict__ bt,
        const float* __restrict__ bp_p, unsigned* ws) {
    unsigned K = ws[WS_TOACT];
    if (K == 0) return;
    if (K > EC) K = EC;
    int row = blockIdx.x;
    float gmax = unmap_f(ws[WS_GMAX]);
    float bp = *bp_p;
    const float4* xr4 = (const float4*)(x + (size_t)row * EC);
    const float4* br4 = (const float4*)(bt + (size_t)row * EC);

    __shared__ unsigned hist[256];
    __shared__ unsigned sb[2];

    unsigned prefix = 0;
    unsigned Kp = K;
    for (int pass = 0; pass < 4; ++pass) {
        const int shift = 24 - 8 * pass;
        for (int i = threadIdx.x; i < 256; i += blockDim.x) hist[i] = 0;
        __syncthreads();
        for (int v = threadIdx.x; v < EC / 4; v += blockDim.x) {
            float4 xv = xr4[v];
            float4 bv = br4[v];
            float xs[4] = {xv.x, xv.y, xv.z, xv.w};
            float bs[4] = {bv.x, bv.y, bv.z, bv.w};
            #pragma unroll
            for (int j = 0; j < 4; ++j) {
                float nb, bo;
                compute_vals(xs[j], bs[j], gmax, bp, &nb, &bo);
                unsigned u = map_f(nb);
                bool match = (pass == 0) || ((u >> (32 - 8 * pass)) == prefix);
                if (match) atomicAdd(&hist[(u >> shift) & 0xFFu], 1u);
            }
        }
        __syncthreads();
        if (threadIdx.x == 0) {
            unsigned cum = 0, bsel = 0, krem = Kp;
            for (int b = 255; b >= 0; --b) {
                unsigned h = hist[b];
                if (cum + h >= Kp) { bsel = (unsigned)b; krem = Kp - cum; break; }
                cum += h;
            }
            sb[0] = (prefix << 8) | bsel;
            sb[1] = krem;
        }
        __syncthreads();
        prefix = sb[0];
        Kp = sb[1];
        __syncthreads();
    }
    unsigned u_t = prefix;
    unsigned ties = Kp;

    __shared__ unsigned s_wcnt[16];
    __shared__ unsigned s_run;
    __shared__ int s_cut;
    if (threadIdx.x == 0) { s_run = 0; s_cut = -1; }
    __syncthreads();
    int nw = (int)blockDim.x >> 6;
    int wid = threadIdx.x >> 6, lane = threadIdx.x & 63;
    const float* xs = x + (size_t)row * EC;
    const float* bs = bt + (size_t)row * EC;
    for (int base0 = 0; base0 < EC; base0 += blockDim.x) {
        int i = base0 + threadIdx.x;
        bool eq = false;
        if (i < EC) {
            float nb, bo;
            compute_vals(xs[i], bs[i], gmax, bp, &nb, &bo);
            eq = (map_f(nb) == u_t);
        }
        unsigned long long bal = __ballot(eq);
        if (lane == 0) s_wcnt[wid] = (unsigned)__popcll(bal);
        __syncthreads();
        unsigned run = s_run;
        unsigned wpre = 0;
        for (int w = 0; w < wid; ++w) wpre += s_wcnt[w];
        if (eq) {
            unsigned r = run + wpre + (unsigned)__popcll(bal & ((1ull << lane) - 1ull));
            if (r == ties - 1) s_cut = i;
        }
        __syncthreads();
        if (threadIdx.x == 0) {
            unsigned tot = 0;
            for (int w = 0; w < nw; ++w) tot += s_wcnt[w];
            s_run = run + tot;
        }
        __syncthreads();
        if (s_run >= ties) break;
    }
    if (threadIdx.x == 0) {
        ws[WS_UT2 + row] = u_t;
        ws[WS_CUT2 + row] = (unsigned)s_cut;
    }
}

// ---------------- Correction apply (gated, dead here) ----------------
__global__ void kfix(const float4* __restrict__ x4, const float4* __restrict__ bt4,
                     const float* __restrict__ bp_p, const unsigned* __restrict__ ws,
                     float* __restrict__ out, float* __restrict__ fb) {
    if (ws[WS_TOACT] == 0) return;
    float gmax = unmap_f(ws[WS_GMAX]);
    float bp = *bp_p;
    const size_t nvec = (size_t)BR * EC / 4;
    size_t stride = (size_t)gridDim.x * blockDim.x;
    for (size_t v = (size_t)blockIdx.x * blockDim.x + threadIdx.x; v < nvec; v += stride) {
        size_t e0 = v << 2;
        int row = (int)(e0 >> 17);
        int col = (int)(e0 & (size_t)(EC - 1));
        unsigned u_t = ws[WS_UT2 + row];
        int cut = (int)ws[WS_CUT2 + row];
        float4 xv = x4[v], bv = bt4[v];
        float xarr[4] = {xv.x, xv.y, xv.z, xv.w};
        float barr[4] = {bv.x, bv.y, bv.z, bv.w};
        #pragma unroll
        for (int j = 0; j < 4; ++j) {
            float nb, bo;
            compute_vals(xarr[j], barr[j], gmax, bp, &nb, &bo);
            unsigned u = map_f(nb);
            if (u > u_t || (u == u_t && (col + j) <= cut)) {
                out[e0 + j] = 1.0f;
                fb[e0 + j] = 0.0f;
            }
        }
    }
}

extern "C" void kernel_launch(void* const* d_in, const int* in_sizes, int n_in,
                              void* d_out, int out_size, void* d_ws, size_t ws_size,
                              hipStream_t stream) {
    const float* x  = (const float*)d_in[0];
    const float* bt = (const float*)d_in[1];
    const float* sp = (const float*)d_in[2];
    const float* bp = (const float*)d_in[3];
    float* out = (float*)d_out;
    float* fb  = out + (size_t)BR * EC;
    unsigned* ws = (unsigned*)d_ws;

    hipMemsetAsync(d_ws, 0, ZERO_BYTES, stream);

    kmax<<<1024, 256, 0, stream>>>((const float4*)x, ws, BR * EC / 4);
    khist<<<BR * CHUNKS, 256, 0, stream>>>((const float4*)x, (const float4*)bt, bp, ws);
    kfind<<<BR, 256, 0, stream>>>(sp, ws);
    kcollect<<<BR * CHUNKS, 256, 0, stream>>>((const float4*)x, (const float4*)bt, bp, ws);
    kfinal<<<BR, 256, 0, stream>>>(ws);
    kmark<<<2048, 256, 0, stream>>>((const float4*)x, (const float4*)bt, bp, ws,
                                    (float4*)out, (float4*)fb);
    kneed<<<1, 64, 0, stream>>>(sp, ws);
    kselect_nb<<<BR, 1024, 0, stream>>>(x, bt, bp, ws);
    kfix<<<2048, 256, 0, stream>>>((const float4*)x, (const float4*)bt, bp, ws, out, fb);
}

// Round 6
// 106.049 us; speedup vs baseline: 4.9075x; 1.0131x over previous
//
#include <hip/hip_runtime.h>

#define BR 64
#define EC 131072
#define BINS 4096
#define CAP 4096
#define LCAP 1024
#define CHUNKS 16
#define CHUNK_V (EC / CHUNKS / 4)   // float4 per chunk = 2048

// ws word-offset layout
#define WS_GMAX 0
#define WS_ACTIVE 1
#define WS_TOACT 2
#define WS_B1 8        // +row
#define WS_KREM 72     // +row
#define WS_UT 136      // +row
#define WS_CUT 200     // +row
#define WS_CCNT 264    // +row
#define WS_UT2 512     // +row (correction branch)
#define WS_CUT2 576    // +row
#define HIST_OFF 1024
#define CAND_U_OFF (HIST_OFF + BR * BINS)
#define CAND_I_OFF (CAND_U_OFF + BR * CAP)
#define ZERO_WORDS CAND_U_OFF          // scalars + per-row slots + histograms
#define ZERO_VEC (ZERO_WORDS / 4)      // 65792 uint4 (ZERO_WORDS % 4 == 0)

// Monotonic float->uint mapping (order-preserving, bijective)
__device__ __forceinline__ unsigned map_f(float f) {
    unsigned b = __float_as_uint(f);
    return (b & 0x80000000u) ? ~b : (b | 0x80000000u);
}
__device__ __forceinline__ float unmap_f(unsigned u) {
    unsigned b = (u & 0x80000000u) ? (u & 0x7FFFFFFFu) : ~u;
    return __uint_as_float(b);
}

// EXACT numpy-op-sequence value computation; contract(off) so every kernel
// computes bit-identical values.
__device__ __forceinline__ void compute_vals(float x, float bt, float gmax, float bp,
                                             float* nb, float* bo) {
#pragma clang fp contract(off)
    float q = x / gmax;
    float t = 1.0f - q;
    float p = t * bp;
    float nbv = bt + p;
    *nb = nbv;
    *bo = fmaxf(x, 0.0f) + nbv;
}

__device__ __forceinline__ unsigned umax_(unsigned a, unsigned b) { return a > b ? a : b; }

// ---------------- Kernel: zero scratch header (replaces slow rocclr fill) --------
__global__ __launch_bounds__(256) void kzero(uint4* __restrict__ ws4) {
    int idx = blockIdx.x * 256 + threadIdx.x;
    int stride = gridDim.x * 256;
    uint4 z = make_uint4(0u, 0u, 0u, 0u);
    for (int i = idx; i < ZERO_VEC; i += stride) ws4[i] = z;
}

// ---------------- Kernel: global max of x ----------------
__global__ void kmax(const float4* __restrict__ x4, unsigned* ws, int nvec) {
    unsigned m = 0;
    int stride = gridDim.x * blockDim.x;
    for (int v = blockIdx.x * blockDim.x + threadIdx.x; v < nvec; v += stride) {
        float4 xv = x4[v];
        m = umax_(m, map_f(xv.x)); m = umax_(m, map_f(xv.y));
        m = umax_(m, map_f(xv.z)); m = umax_(m, map_f(xv.w));
    }
    for (int off = 32; off; off >>= 1) m = umax_(m, __shfl_down(m, off, 64));
    __shared__ unsigned sm[16];
    int wid = threadIdx.x >> 6, lane = threadIdx.x & 63;
    if (lane == 0) sm[wid] = m;
    __syncthreads();
    if (threadIdx.x == 0) {
        unsigned mm = sm[0];
        int nw = blockDim.x >> 6;
        for (int w = 1; w < nw; ++w) mm = umax_(mm, sm[w]);
        atomicMax(ws, mm);
    }
}

// ---------------- Kernel: per-row 4096-bin histogram of top-12 bits ----------------
__global__ __launch_bounds__(256) void khist(const float4* __restrict__ x4,
                                             const float4* __restrict__ bt4,
                                             const float* __restrict__ bp_p,
                                             unsigned* __restrict__ ws) {
    __shared__ unsigned h[2][BINS];
    for (int i = threadIdx.x; i < 2 * BINS; i += 256) h[0][i] = 0;
    int row = blockIdx.x >> 4;
    int chunk = blockIdx.x & (CHUNKS - 1);
    int cpy = threadIdx.x >> 7;   // wave-pair id
    float gmax = unmap_f(ws[WS_GMAX]);
    float bp = *bp_p;
    size_t base = (size_t)row * (EC / 4) + (size_t)chunk * CHUNK_V;
    __syncthreads();
    for (int v = threadIdx.x; v < CHUNK_V; v += 256) {
        float4 xv = x4[base + v];
        float4 bv = bt4[base + v];
        float xs[4] = {xv.x, xv.y, xv.z, xv.w};
        float bs[4] = {bv.x, bv.y, bv.z, bv.w};
        #pragma unroll
        for (int j = 0; j < 4; ++j) {
            float nb, bo;
            compute_vals(xs[j], bs[j], gmax, bp, &nb, &bo);
            atomicAdd(&h[cpy][map_f(bo) >> 20], 1u);
        }
    }
    __syncthreads();
    unsigned* gh = ws + HIST_OFF + (size_t)row * BINS;
    int rot = chunk * 256;
    for (int i0 = threadIdx.x; i0 < BINS; i0 += 256) {
        int i = (i0 + rot) & (BINS - 1);
        unsigned v = h[0][i] + h[1][i];
        if (v) atomicAdd(&gh[i], v);   // fire-and-forget
    }
}

// ---------------- Kernel: find bin containing K-th largest, per row ----------------
__global__ __launch_bounds__(256) void kfind(const float* __restrict__ sp,
                                             unsigned* __restrict__ ws) {
    int row = blockIdx.x;
    unsigned K = (unsigned)ceilf(sp[1] * (float)EC);
    if (K > EC) K = EC;
    if (K == 0) K = 1;
    const unsigned* gh = ws + HIST_OFF + (size_t)row * BINS;
    __shared__ unsigned ssum[256];
    __shared__ unsigned sabove[256];
    int t = threadIdx.x;
    unsigned hv[16];
    unsigned s = 0;
    #pragma unroll
    for (int j = 0; j < 16; ++j) { hv[j] = gh[t * 16 + j]; s += hv[j]; }
    ssum[t] = s;
    __syncthreads();
    if (t == 0) {
        unsigned acc = 0;
        for (int q = 255; q >= 0; --q) { sabove[q] = acc; acc += ssum[q]; }
    }
    __syncthreads();
    unsigned cum = sabove[t];
    for (int j = 15; j >= 0; --j) {
        unsigned h = hv[j];
        if (cum < K && cum + h >= K) {
            ws[WS_B1 + row] = (unsigned)(t * 16 + j);
            ws[WS_KREM + row] = K - cum;
        }
        cum += h;
    }
}

// ---------------- Kernel: collect candidates (block-aggregated reservation) -------
__global__ __launch_bounds__(256) void kcollect(const float4* __restrict__ x4,
                                                const float4* __restrict__ bt4,
                                                const float* __restrict__ bp_p,
                                                unsigned* __restrict__ ws) {
    __shared__ unsigned lu[LCAP], li[LCAP];
    __shared__ unsigned lcnt, gbase;
    if (threadIdx.x == 0) lcnt = 0;
    int row = blockIdx.x >> 4;
    int chunk = blockIdx.x & (CHUNKS - 1);
    unsigned b1 = ws[WS_B1 + row];
    float gmax = unmap_f(ws[WS_GMAX]);
    float bp = *bp_p;
    unsigned* cu = ws + CAND_U_OFF + (size_t)row * CAP;
    unsigned* ci = ws + CAND_I_OFF + (size_t)row * CAP;
    size_t base = (size_t)row * (EC / 4) + (size_t)chunk * CHUNK_V;
    int ebase = chunk * (EC / CHUNKS);
    __syncthreads();
    for (int v = threadIdx.x; v < CHUNK_V; v += 256) {
        float4 xv = x4[base + v];
        float4 bv = bt4[base + v];
        float xs[4] = {xv.x, xv.y, xv.z, xv.w};
        float bs[4] = {bv.x, bv.y, bv.z, bv.w};
        #pragma unroll
        for (int j = 0; j < 4; ++j) {
            float nb, bo;
            compute_vals(xs[j], bs[j], gmax, bp, &nb, &bo);
            unsigned u = map_f(bo);
            if ((u >> 20) == b1) {
                unsigned p = atomicAdd(&lcnt, 1u);
                if (p < LCAP) {
                    lu[p] = u; li[p] = (unsigned)(ebase + v * 4 + j);
                } else {  // overflow fallback (rare)
                    unsigned gp = atomicAdd(&ws[WS_CCNT + row], 1u);
                    if (gp < CAP) { cu[gp] = u; ci[gp] = (unsigned)(ebase + v * 4 + j); }
                }
            }
        }
    }
    __syncthreads();
    unsigned n = lcnt < LCAP ? lcnt : LCAP;
    if (threadIdx.x == 0) gbase = atomicAdd(&ws[WS_CCNT + row], n);
    __syncthreads();
    unsigned gb = gbase;
    for (unsigned i = threadIdx.x; i < n; i += 256) {
        unsigned gp = gb + i;
        if (gp < CAP) { cu[gp] = lu[i]; ci[gp] = li[i]; }
    }
}

// ---------------- Kernel: exact select + stable tie-cut among candidates ----------
// Radix only over the low 20 bits (top 12 known = b1); fully parallel tie-cut.
__global__ __launch_bounds__(256) void kfinal(unsigned* __restrict__ ws) {
    int row = blockIdx.x;
    unsigned n = ws[WS_CCNT + row];
    if (n > CAP) n = CAP;
    unsigned b1 = ws[WS_B1 + row];
    unsigned K = ws[WS_KREM + row];   // rank of target within this bin
    const unsigned* cu = ws + CAND_U_OFF + (size_t)row * CAP;
    const unsigned* ci = ws + CAND_I_OFF + (size_t)row * CAP;
    __shared__ unsigned su[CAP];
    __shared__ unsigned marr[CAP];
    __shared__ unsigned hist[256];
    __shared__ unsigned scan[256];
    __shared__ unsigned sb[2];
    __shared__ unsigned mcnt;
    for (unsigned i = threadIdx.x; i < n; i += 256) su[i] = cu[i];
    if (threadIdx.x == 0) mcnt = 0;
    __syncthreads();
    int t = threadIdx.x;

    unsigned pv = b1 << 20;   // value bits fixed so far
    unsigned Kp = K;
    const int shifts[3] = {12, 4, 0};
    const unsigned wmask[3] = {0xFFu, 0xFFu, 0xFu};
    const unsigned pmask[3] = {0xFFF00000u, 0xFFFFF000u, 0xFFFFFFF0u};
    for (int pass = 0; pass < 3; ++pass) {
        int shift = shifts[pass];
        unsigned msk = wmask[pass];
        hist[t] = 0;
        __syncthreads();
        for (unsigned i = t; i < n; i += 256) {
            unsigned u = su[i];
            if ((u & pmask[pass]) == pv) atomicAdd(&hist[(u >> shift) & msk], 1u);
        }
        __syncthreads();
        // parallel inclusive suffix scan: scan[t] = sum_{b>=t} hist[b]
        unsigned my = hist[t];
        scan[t] = my;
        __syncthreads();
        for (int off = 1; off < 256; off <<= 1) {
            unsigned v = (t + off < 256) ? scan[t + off] : 0u;
            __syncthreads();
            scan[t] += v;
            __syncthreads();
        }
        unsigned incl = scan[t], excl = incl - my;
        if ((unsigned)t <= msk && excl < Kp && incl >= Kp) {
            sb[0] = pv | ((unsigned)t << shift);
            sb[1] = Kp - excl;
        }
        __syncthreads();
        pv = sb[0];
        Kp = sb[1];
        __syncthreads();
    }
    unsigned u_t = pv, krem2 = Kp;

    // compact matching candidates' original indices (typically 1 match)
    for (unsigned i = t; i < n; i += 256)
        if (su[i] == u_t) { unsigned p = atomicAdd(&mcnt, 1u); if (p < CAP) marr[p] = ci[i]; }
    __syncthreads();
    unsigned m = mcnt < CAP ? mcnt : CAP;
    // parallel rank among matches: cut = index with exactly krem2-1 smaller indices
    for (unsigned i = t; i < m; i += 256) {
        unsigned myidx = marr[i];
        unsigned r = 0;
        for (unsigned j = 0; j < m; ++j) r += (marr[j] < myidx) ? 1u : 0u;
        if (r == krem2 - 1) {
            ws[WS_UT + row] = u_t;
            ws[WS_CUT + row] = myidx;
        }
    }
}

// ---------------- Kernel: mark + write both outputs + count active ----------------
__global__ void kmark(const float4* __restrict__ x4, const float4* __restrict__ bt4,
                      const float* __restrict__ bp_p, unsigned* ws,
                      float4* __restrict__ out4, float4* __restrict__ fb4) {
    float gmax = unmap_f(ws[WS_GMAX]);
    float bp = *bp_p;
    unsigned cnt = 0;
    const size_t nvec = (size_t)BR * EC / 4;
    size_t stride = (size_t)gridDim.x * blockDim.x;
    for (size_t v = (size_t)blockIdx.x * blockDim.x + threadIdx.x; v < nvec; v += stride) {
        size_t e0 = v << 2;
        int row = (int)(e0 >> 17);
        int col = (int)(e0 & (size_t)(EC - 1));
        unsigned u_t = ws[WS_UT + row];
        int cut = (int)ws[WS_CUT + row];
        float4 xv = x4[v], bv = bt4[v];
        float xarr[4] = {xv.x, xv.y, xv.z, xv.w};
        float barr[4] = {bv.x, bv.y, bv.z, bv.w};
        float o[4], f[4];
        #pragma unroll
        for (int j = 0; j < 4; ++j) {
            float nb, bo;
            compute_vals(xarr[j], barr[j], gmax, bp, &nb, &bo);
            unsigned u = map_f(bo);
            bool sel = (u > u_t) || ((u == u_t) && ((col + j) <= cut));
            bool saved = sel && (u > 0x80000000u);  // boosted > 0
            o[j] = saved ? 1.0f : 0.0f;
            f[j] = saved ? 0.0f : nb;
            cnt += saved ? 1u : 0u;
        }
        out4[v] = make_float4(o[0], o[1], o[2], o[3]);
        fb4[v] = make_float4(f[0], f[1], f[2], f[3]);
    }
    for (int off = 32; off; off >>= 1) cnt += __shfl_down(cnt, off, 64);
    __shared__ unsigned sc;
    if (threadIdx.x == 0) sc = 0;
    __syncthreads();
    if ((threadIdx.x & 63) == 0) atomicAdd(&sc, cnt);
    __syncthreads();
    if (threadIdx.x == 0) atomicAdd(&ws[WS_ACTIVE], sc);
}

// ---------------- Correction branch: per-row select on new_boost (gated, dead here) ----
// Computes to_activate from ACTIVE itself (kneed folded in); block 0 publishes
// WS_TOACT for kfix's gate (kzero pre-zeroed it for the no-need case).
__global__ __launch_bounds__(1024) void kselect_nb(
        const float* __restrict__ x, const float* __restrict__ bt,
        const float* __restrict__ sp, const float* __restrict__ bp_p,
        unsigned* ws) {
    float min_active = floorf(sp[0] * (float)EC);
    float active = (float)ws[WS_ACTIVE];
    if (!(active < min_active)) return;   // WS_TOACT stays 0 (kzero)
    unsigned K = (unsigned)ceilf(min_active - active);
    if (blockIdx.x == 0 && threadIdx.x == 0) ws[WS_TOACT] = K;
    if (K > EC) K = EC;
    int row = blockIdx.x;
    float gmax = unmap_f(ws[WS_GMAX]);
    float bp = *bp_p;
    const float4* xr4 = (const float4*)(x + (size_t)row * EC);
    const float4* br4 = (const float4*)(bt + (size_t)row * EC);

    __shared__ unsigned hist[256];
    __shared__ unsigned sb[2];

    unsigned prefix = 0;
    unsigned Kp = K;
    for (int pass = 0; pass < 4; ++pass) {
        const int shift = 24 - 8 * pass;
        for (int i = threadIdx.x; i < 256; i += blockDim.x) hist[i] = 0;
        __syncthreads();
        for (int v = threadIdx.x; v < EC / 4; v += blockDim.x) {
            float4 xv = xr4[v];
            float4 bv = br4[v];
            float xs[4] = {xv.x, xv.y, xv.z, xv.w};
            float bs[4] = {bv.x, bv.y, bv.z, bv.w};
            #pragma unroll
            for (int j = 0; j < 4; ++j) {
                float nb, bo;
                compute_vals(xs[j], bs[j], gmax, bp, &nb, &bo);
                unsigned u = map_f(nb);
                bool match = (pass == 0) || ((u >> (32 - 8 * pass)) == prefix);
                if (match) atomicAdd(&hist[(u >> shift) & 0xFFu], 1u);
            }
        }
        __syncthreads();
        if (threadIdx.x == 0) {
            unsigned cum = 0, bsel = 0, krem = Kp;
            for (int b = 255; b >= 0; --b) {
                unsigned h = hist[b];
                if (cum + h >= Kp) { bsel = (unsigned)b; krem = Kp - cum; break; }
                cum += h;
            }
            sb[0] = (prefix << 8) | bsel;
            sb[1] = krem;
        }
        __syncthreads();
        prefix = sb[0];
        Kp = sb[1];
        __syncthreads();
    }
    unsigned u_t = prefix;
    unsigned ties = Kp;

    __shared__ unsigned s_wcnt[16];
    __shared__ unsigned s_run;
    __shared__ int s_cut;
    if (threadIdx.x == 0) { s_run = 0; s_cut = -1; }
    __syncthreads();
    int nw = (int)blockDim.x >> 6;
    int wid = threadIdx.x >> 6, lane = threadIdx.x & 63;
    const float* xs = x + (size_t)row * EC;
    const float* bs = bt + (size_t)row * EC;
    for (int base0 = 0; base0 < EC; base0 += blockDim.x) {
        int i = base0 + threadIdx.x;
        bool eq = false;
        if (i < EC) {
            float nb, bo;
            compute_vals(xs[i], bs[i], gmax, bp, &nb, &bo);
            eq = (map_f(nb) == u_t);
        }
        unsigned long long bal = __ballot(eq);
        if (lane == 0) s_wcnt[wid] = (unsigned)__popcll(bal);
        __syncthreads();
        unsigned run = s_run;
        unsigned wpre = 0;
        for (int w = 0; w < wid; ++w) wpre += s_wcnt[w];
        if (eq) {
            unsigned r = run + wpre + (unsigned)__popcll(bal & ((1ull << lane) - 1ull));
            if (r == ties - 1) s_cut = i;
        }
        __syncthreads();
        if (threadIdx.x == 0) {
            unsigned tot = 0;
            for (int w = 0; w < nw; ++w) tot += s_wcnt[w];
            s_run = run + tot;
        }
        __syncthreads();
        if (s_run >= ties) break;
    }
    if (threadIdx.x == 0) {
        ws[WS_UT2 + row] = u_t;
        ws[WS_CUT2 + row] = (unsigned)s_cut;
    }
}

// ---------------- Correction apply (gated, dead here) ----------------
__global__ void kfix(const float4* __restrict__ x4, const float4* __restrict__ bt4,
                     const float* __restrict__ bp_p, const unsigned* __restrict__ ws,
                     float* __restrict__ out, float* __restrict__ fb) {
    if (ws[WS_TOACT] == 0) return;
    float gmax = unmap_f(ws[WS_GMAX]);
    float bp = *bp_p;
    const size_t nvec = (size_t)BR * EC / 4;
    size_t stride = (size_t)gridDim.x * blockDim.x;
    for (size_t v = (size_t)blockIdx.x * blockDim.x + threadIdx.x; v < nvec; v += stride) {
        size_t e0 = v << 2;
        int row = (int)(e0 >> 17);
        int col = (int)(e0 & (size_t)(EC - 1));
        unsigned u_t = ws[WS_UT2 + row];
        int cut = (int)ws[WS_CUT2 + row];
        float4 xv = x4[v], bv = bt4[v];
        float xarr[4] = {xv.x, xv.y, xv.z, xv.w};
        float barr[4] = {bv.x, bv.y, bv.z, bv.w};
        #pragma unroll
        for (int j = 0; j < 4; ++j) {
            float nb, bo;
            compute_vals(xarr[j], barr[j], gmax, bp, &nb, &bo);
            unsigned u = map_f(nb);
            if (u > u_t || (u == u_t && (col + j) <= cut)) {
                out[e0 + j] = 1.0f;
                fb[e0 + j] = 0.0f;
            }
        }
    }
}

extern "C" void kernel_launch(void* const* d_in, const int* in_sizes, int n_in,
                              void* d_out, int out_size, void* d_ws, size_t ws_size,
                              hipStream_t stream) {
    const float* x  = (const float*)d_in[0];
    const float* bt = (const float*)d_in[1];
    const float* sp = (const float*)d_in[2];
    const float* bp = (const float*)d_in[3];
    float* out = (float*)d_out;
    float* fb  = out + (size_t)BR * EC;
    unsigned* ws = (unsigned*)d_ws;

    kzero<<<512, 256, 0, stream>>>((uint4*)d_ws);
    kmax<<<1024, 256, 0, stream>>>((const float4*)x, ws, BR * EC / 4);
    khist<<<BR * CHUNKS, 256, 0, stream>>>((const float4*)x, (const float4*)bt, bp, ws);
    kfind<<<BR, 256, 0, stream>>>(sp, ws);
    kcollect<<<BR * CHUNKS, 256, 0, stream>>>((const float4*)x, (const float4*)bt, bp, ws);
    kfinal<<<BR, 256, 0, stream>>>(ws);
    kmark<<<2048, 256, 0, stream>>>((const float4*)x, (const float4*)bt, bp, ws,
                                    (float4*)out, (float4*)fb);
    kselect_nb<<<BR, 1024, 0, stream>>>(x, bt, sp, bp, ws);
    kfix<<<2048, 256, 0, stream>>>((const float4*)x, (const float4*)bt, bp, ws, out, fb);
}